// Round 8
// baseline (518.467 us; speedup 1.0000x reference)
//
#include <hip/hip_runtime.h>

// pSGM non-local block, MI355X (round 18: cross-iteration register pipelining).
// r17: XCD pinning cut FETCH 37->30MB but dur flat -> L2 misses not critical path.
// Remaining fit to ALL data: register starvation serializes loads. VGPR=96 =
// yacc(64)+af(32) alone -> compiler recycles a tiny pool for 24 loads/iter ->
// MLP~1-2 (187cy/load = one full L2 latency each). Explains r13 (more waves:
// per-SIMD in-flight still ~6), r15 (fewer loads & fewer live dests: slower),
// r16 (in-iter reorder can't beat the allocator).
// r18: software-pipeline with NAMED live regs: phi(s) resident (pc0/pc1, 64r);
// after f-phase reads, issue phi(s+1) into same names (in flight across
// mk_pa+y-MFMA+back-edge); g(s) issued at top, used at end. 24 loads in
// flight/wave, ~230 VGPR < 256 cap -> 2 waves/SIMD, 48 in flight/SIMD.
// Last-iter prefetch overreads <=8KB into adjacent ws buffer (safe).
// k_stats: same transform (theta t+2 prefetch). k_pv falsifier: VGPR_Count.

#define B_ 2
#define C_ 256
#define CI_ 128
#define NPIX 12544
#define NS 3136
#define NSL 28

typedef short bf16x8 __attribute__((ext_vector_type(8)));
typedef float f32x4 __attribute__((ext_vector_type(4)));

__device__ __forceinline__ short f2bf(float f) {
    unsigned u = __float_as_uint(f);
    u = (u + 0x7fff + ((u >> 16) & 1)) >> 16;   // RNE
    return (short)u;
}
__device__ __forceinline__ float bf2f(short s) {
    return __uint_as_float(((unsigned)(unsigned short)s) << 16);
}
__device__ __forceinline__ short f2h(float f) {
    _Float16 h = (_Float16)f;
    short s;
    __builtin_memcpy(&s, &h, 2);
    return s;
}
__device__ __forceinline__ float h2f(short s) {
    _Float16 h;
    __builtin_memcpy(&h, &s, 2);
    return (float)h;
}
__device__ __forceinline__ f32x4 mfma16(bf16x8 a, bf16x8 b, f32x4 c) {
    return __builtin_amdgcn_mfma_f32_16x16x32_bf16(a, b, c, 0, 0, 0);
}
// perm layout, K=128 operands (theta/phi/g/y): frag-contiguous 1KB wave-loads
__device__ __forceinline__ size_t pidx(int r, int k) {
    return (size_t)((r >> 4) * 4 + (k >> 5)) * 512 +
           (size_t)(((k >> 3) & 3) * 128 + (r & 15) * 8 + (k & 7));
}
// perm layout, K=256 operands (conv A inputs)
__device__ __forceinline__ size_t pidx256(int r, int k) {
    return (size_t)((r >> 4) * 8 + (k >> 5)) * 512 +
           (size_t)(((k >> 3) & 3) * 128 + (r & 15) * 8 + (k & 7));
}

struct Frag3 { bf16x8 h, m, l; };
struct Frag2 { bf16x8 h, m; };

__device__ __forceinline__ Frag3 ld3(const short* __restrict__ h, const short* __restrict__ m,
                                     const short* __restrict__ l, size_t off) {
    Frag3 f;
    f.h = *(const bf16x8*)(h + off);
    f.m = *(const bf16x8*)(m + off);
    f.l = *(const bf16x8*)(l + off);
    return f;
}
__device__ __forceinline__ Frag2 ld2(const short* __restrict__ h, const short* __restrict__ m,
                                     size_t off) {
    Frag2 f;
    f.h = *(const bf16x8*)(h + off);
    f.m = *(const bf16x8*)(m + off);
    return f;
}
// 5-term conv product: A 2-plane (exact to 2^-17) x W 3-plane
__device__ __forceinline__ f32x4 mm5(Frag2 a, Frag3 w, f32x4 acc) {
    acc = mfma16(a.h, w.l, acc);
    acc = mfma16(a.m, w.m, acc);
    acc = mfma16(a.m, w.h, acc);
    acc = mfma16(a.h, w.m, acc);
    acc = mfma16(a.h, w.h, acc);
    return acc;
}
__device__ __forceinline__ f32x4 mm3(Frag2 a, Frag2 b, f32x4 acc) {
    acc = mfma16(a.m, b.h, acc);
    acc = mfma16(a.h, b.m, acc);
    acc = mfma16(a.h, b.h, acc);
    return acc;
}
// 2-term f-emulation: streamed operand h-plane only (drops a_m * b.h term,
// |err| ~ 2^-9*sqrt(128) ~ 0.03 in f) — used in k_stats only (S denominator)
__device__ __forceinline__ f32x4 mm2s(bf16x8 ah, Frag2 b, f32x4 acc) {
    acc = mfma16(ah, b.m, acc);
    acc = mfma16(ah, b.h, acc);
    return acc;
}
// build PV A-frag from f^T tile pair. ALL shuffles unconditional (full exec mask);
// select on materialized registers only (v_cndmask, no divergent branch around shfl).
__device__ __forceinline__ bf16x8 mk_pa(f32x4 f0, f32x4 f1, int srcLo, int srcHi, bool hiTile) {
    unsigned t0d0 = (unsigned)(unsigned short)f2bf(__expf(f0[0] - 32.f)) |
                    ((unsigned)(unsigned short)f2bf(__expf(f0[1] - 32.f)) << 16);
    unsigned t0d1 = (unsigned)(unsigned short)f2bf(__expf(f0[2] - 32.f)) |
                    ((unsigned)(unsigned short)f2bf(__expf(f0[3] - 32.f)) << 16);
    unsigned t1d0 = (unsigned)(unsigned short)f2bf(__expf(f1[0] - 32.f)) |
                    ((unsigned)(unsigned short)f2bf(__expf(f1[1] - 32.f)) << 16);
    unsigned t1d1 = (unsigned)(unsigned short)f2bf(__expf(f1[2] - 32.f)) |
                    ((unsigned)(unsigned short)f2bf(__expf(f1[3] - 32.f)) << 16);
    unsigned lo0t0 = __shfl(t0d0, srcLo), lo1t0 = __shfl(t0d1, srcLo);
    unsigned hi0t0 = __shfl(t0d0, srcHi), hi1t0 = __shfl(t0d1, srcHi);
    unsigned lo0t1 = __shfl(t1d0, srcLo), lo1t1 = __shfl(t1d1, srcLo);
    unsigned hi0t1 = __shfl(t1d0, srcHi), hi1t1 = __shfl(t1d1, srcHi);
    unsigned pd[4];
    pd[0] = hiTile ? lo0t1 : lo0t0;
    pd[1] = hiTile ? lo1t1 : lo1t0;
    pd[2] = hiTile ? hi0t1 : hi0t0;
    pd[3] = hiTile ? hi1t1 : hi1t0;
    bf16x8 pa;
    __builtin_memcpy(&pa, pd, 16);
    return pa;
}

// ---- merged weight pre-split: theta/phi 3-plane, g/W 2-plane ----
__global__ void k_splitw(const float* __restrict__ thw, const float* __restrict__ phw,
                         const float* __restrict__ gw, const float* __restrict__ Ww,
                         short* __restrict__ thwH, short* __restrict__ thwM, short* __restrict__ thwL,
                         short* __restrict__ phwH, short* __restrict__ phwM, short* __restrict__ phwL,
                         short* __restrict__ gwH, short* __restrict__ gwM,
                         short* __restrict__ wwH, short* __restrict__ wwM) {
    int i = blockIdx.x * 256 + threadIdx.x;
    int which = i >> 15, j = i & 32767;
    if (which == 0) {
        float x = thw[j];
        unsigned uh = __float_as_uint(x) & 0xffff0000u;
        float r1 = x - __uint_as_float(uh);
        unsigned um = __float_as_uint(r1) & 0xffff0000u;
        thwH[j] = (short)(uh >> 16);
        thwM[j] = (short)(um >> 16);
        thwL[j] = f2bf(r1 - __uint_as_float(um));
    } else if (which == 1) {
        float x = phw[j];
        unsigned uh = __float_as_uint(x) & 0xffff0000u;
        float r1 = x - __uint_as_float(uh);
        unsigned um = __float_as_uint(r1) & 0xffff0000u;
        phwH[j] = (short)(uh >> 16);
        phwM[j] = (short)(um >> 16);
        phwL[j] = f2bf(r1 - __uint_as_float(um));
    } else if (which == 2) {
        float x = gw[j];
        unsigned uh = __float_as_uint(x) & 0xffff0000u;
        gwH[j] = (short)(uh >> 16);
        gwM[j] = f2bf(x - __uint_as_float(uh));
    } else {
        float x = Ww[j];
        unsigned uh = __float_as_uint(x) & 0xffff0000u;
        wwH[j] = (short)(uh >> 16);
        wwM[j] = f2bf(x - __uint_as_float(uh));
    }
}

// ---- transpose + 2-plane split into perm(K=256) ----
__global__ void k_transpose2p(const float* __restrict__ src, short* __restrict__ oh,
                              short* __restrict__ om) {
    __shared__ float tile[32][33];
    int b = blockIdx.z;
    const float* s = src + (size_t)b * C_ * NPIX;
    size_t ob = (size_t)b * NPIX * C_;
    int p0 = blockIdx.x * 32, c0 = blockIdx.y * 32;
    for (int i = threadIdx.y; i < 32; i += 8)
        tile[i][threadIdx.x] = s[(size_t)(c0 + i) * NPIX + p0 + threadIdx.x];
    __syncthreads();
    for (int i = threadIdx.y; i < 32; i += 8) {
        float v = tile[threadIdx.x][i];
        unsigned uh = __float_as_uint(v) & 0xffff0000u;
        size_t o = ob + pidx256(p0 + i, c0 + threadIdx.x);
        oh[o] = (short)(uh >> 16);
        om[o] = f2bf(v - __uint_as_float(uh));
    }
}

// ---- theta conv: 5-term, 2 row-tiles/block. grid (NPIX/32, B), block 128 ----
__global__ __launch_bounds__(128, 2) void k_conv5(const short* __restrict__ AH,
        const short* __restrict__ AM,
        const short* __restrict__ WH, const short* __restrict__ WM, const short* __restrict__ WL,
        const float* __restrict__ bias, short* __restrict__ oh, short* __restrict__ om) {
    int wid = threadIdx.x >> 6, lane = threadIdx.x & 63;
    int quad = lane >> 4, l16 = lane & 15;
    int b = blockIdx.y;
    size_t ab = (size_t)b * NPIX * C_;
    size_t ob = (size_t)b * NPIX * CI_;
    int rt0 = blockIdx.x * 2;
    f32x4 acc[2][4] = {};
    for (int kt = 0; kt < 8; kt++) {
        Frag2 a0 = ld2(AH, AM, ab + ((size_t)rt0 * 8 + kt) * 512 + lane * 8);
        Frag2 a1 = ld2(AH, AM, ab + ((size_t)(rt0 + 1) * 8 + kt) * 512 + lane * 8);
#pragma unroll
        for (int c4 = 0; c4 < 4; c4++) {
            int c = (wid * 4 + c4) * 16 + l16;
            Frag3 w = ld3(WH, WM, WL, (size_t)c * C_ + kt * 32 + quad * 8);
            acc[0][c4] = mm5(a0, w, acc[0][c4]);
            acc[1][c4] = mm5(a1, w, acc[1][c4]);
        }
    }
#pragma unroll
    for (int t2 = 0; t2 < 2; t2++)
#pragma unroll
        for (int c4 = 0; c4 < 4; c4++) {
            int c = (wid * 4 + c4) * 16 + l16;
            float bv = bias[c];
#pragma unroll
            for (int r = 0; r < 4; r++) {
                float v = acc[t2][c4][r] + bv;
                unsigned uh = __float_as_uint(v) & 0xffff0000u;
                size_t o = ob + pidx((rt0 + t2) * 16 + quad * 4 + r, c);
                oh[o] = (short)(uh >> 16);
                om[o] = f2bf(v - __uint_as_float(uh));
            }
        }
}

// ---- fused phi(5-term->fp32) + g(3-term->bf16), 2 row-tiles/block ----
__global__ __launch_bounds__(128, 2) void k_convxg5(const short* __restrict__ AH,
        const short* __restrict__ AM,
        const short* __restrict__ PH, const short* __restrict__ PM, const short* __restrict__ PL,
        const short* __restrict__ GH, const short* __restrict__ GM,
        const float* __restrict__ pbias, const float* __restrict__ gbias,
        float* __restrict__ pfull, short* __restrict__ gout) {
    int wid = threadIdx.x >> 6, lane = threadIdx.x & 63;
    int quad = lane >> 4, l16 = lane & 15;
    int b = blockIdx.y;
    size_t ab = (size_t)b * NPIX * C_;
    float* Pb = pfull + (size_t)b * NPIX * CI_;
    short* Gb = gout + (size_t)b * NPIX * CI_;
    int rt0 = blockIdx.x * 2;
    f32x4 accp[2][4] = {}, accg[2][4] = {};
    for (int kt = 0; kt < 8; kt++) {
        Frag2 a0 = ld2(AH, AM, ab + ((size_t)rt0 * 8 + kt) * 512 + lane * 8);
        Frag2 a1 = ld2(AH, AM, ab + ((size_t)(rt0 + 1) * 8 + kt) * 512 + lane * 8);
#pragma unroll
        for (int c4 = 0; c4 < 4; c4++) {
            int c = (wid * 4 + c4) * 16 + l16;
            size_t wo = (size_t)c * C_ + kt * 32 + quad * 8;
            Frag3 wp = ld3(PH, PM, PL, wo);
            accp[0][c4] = mm5(a0, wp, accp[0][c4]);
            accp[1][c4] = mm5(a1, wp, accp[1][c4]);
            Frag2 wg = ld2(GH, GM, wo);
            accg[0][c4] = mm3(a0, wg, accg[0][c4]);
            accg[1][c4] = mm3(a1, wg, accg[1][c4]);
        }
    }
#pragma unroll
    for (int t2 = 0; t2 < 2; t2++)
#pragma unroll
        for (int c4 = 0; c4 < 4; c4++) {
            int c = (wid * 4 + c4) * 16 + l16;
            float pbv = pbias[c], gbv = gbias[c];
#pragma unroll
            for (int r = 0; r < 4; r++) {
                size_t o = (size_t)((rt0 + t2) * 16 + quad * 4 + r) * CI_ + c;
                Pb[o] = accp[t2][c4][r] + pbv;
                Gb[o] = f2bf(accg[t2][c4][r] + gbv);
            }
        }
}

// ---- pool: pfull fp32 -> phi 2-plane PERM; gfull bf16 -> gcf fp32 (ci, m) ----
__global__ void k_pool(const float* __restrict__ pfull, const short* __restrict__ gfull,
                       short* __restrict__ pth, short* __restrict__ ptm,
                       float* __restrict__ gcf) {
    int b = blockIdx.y;
    int idx = blockIdx.x * 256 + threadIdx.x;       // idx = m*128 + ci
    int ci = idx & 127, m = idx >> 7;
    int t = m / 196, r2i = m - t * 196;
    int h2 = r2i / 14, w2 = r2i - h2 * 14;
    size_t p = (size_t)t * 784 + (size_t)(2 * h2) * 28 + 2 * w2;
    size_t i0 = (size_t)b * NPIX * CI_ + p * CI_ + ci;
    float pv = fmaxf(fmaxf(pfull[i0], pfull[i0 + CI_]),
                     fmaxf(pfull[i0 + 28 * CI_], pfull[i0 + 29 * CI_]));
    unsigned uh = __float_as_uint(pv) & 0xffff0000u;
    size_t ob = (size_t)b * NS * CI_ + pidx(m, ci);
    pth[ob] = (short)(uh >> 16);
    ptm[ob] = f2bf(pv - __uint_as_float(uh));
    float g0 = fmaxf(fmaxf(bf2f(gfull[i0]), bf2f(gfull[i0 + CI_])),
                     fmaxf(bf2f(gfull[i0 + 28 * CI_]), bf2f(gfull[i0 + 29 * CI_])));
    gcf[(size_t)b * NS * CI_ + (size_t)ci * NS + m] = g0;
}

// ---- stats: S[m]=sum_n exp(f-32); theta stream h-plane only, t+2 reg prefetch;
//      XCD-pinned: wgid = (tchunk*2+b) + 56*x. grid (49*56), block 128 ----
__global__ __launch_bounds__(128, 2) void k_stats(
        const short* __restrict__ thh, const short* __restrict__ thm,
        const short* __restrict__ phh, const short* __restrict__ phm,
        float* __restrict__ Spart) {
    (void)thm;
    int wid = threadIdx.x >> 6, lane = threadIdx.x & 63;
    int quad = lane >> 4, l16 = lane & 15;
    int wg = blockIdx.x;
    int p = wg % 56;                                // (tchunk, b) pair -> pins XCD
    int bx = wg / 56;                               // 0..48
    int b = p & 1, ychunk = p >> 1;
    size_t tb = (size_t)b * NPIX * CI_, pb = (size_t)b * NS * CI_;
    int mtA = bx * 4 + wid * 2;                     // m-tiles mtA, mtA+1
    Frag2 bfA[4], bfB[4];
#pragma unroll
    for (int kk = 0; kk < 4; kk++) {
        bfA[kk] = ld2(phh, phm, pb + ((size_t)mtA * 4 + kk) * 512 + lane * 8);
        bfB[kk] = ld2(phh, phm, pb + ((size_t)(mtA + 1) * 4 + kk) * 512 + lane * 8);
    }
    float SA = 0.f, SB = 0.f;
    int t_beg = ychunk * (784 / NSL), t_end = t_beg + 784 / NSL;
    // cross-iteration pipeline: theta(t) resident; t+2 loads issued after reads.
    bf16x8 x0[4], x1[4];
#pragma unroll
    for (int kk = 0; kk < 4; kk++) {
        x0[kk] = *(const bf16x8*)(thh + tb + ((size_t)t_beg * 4 + kk) * 512 + lane * 8);
        x1[kk] = *(const bf16x8*)(thh + tb + ((size_t)(t_beg + 1) * 4 + kk) * 512 + lane * 8);
    }
    for (int t = t_beg; t < t_end; t += 2) {
        f32x4 aA0 = {}, aA1 = {}, aB0 = {}, aB1 = {};
#pragma unroll
        for (int kk = 0; kk < 4; kk++) {
            aA0 = mm2s(x0[kk], bfA[kk], aA0);
            aA1 = mm2s(x1[kk], bfA[kk], aA1);
            aB0 = mm2s(x0[kk], bfB[kk], aB0);
            aB1 = mm2s(x1[kk], bfB[kk], aB1);
        }
        // prefetch theta(t+2, t+3) — benign <=8KB overread on last iteration
#pragma unroll
        for (int kk = 0; kk < 4; kk++) {
            x0[kk] = *(const bf16x8*)(thh + tb + ((size_t)(t + 2) * 4 + kk) * 512 + lane * 8);
            x1[kk] = *(const bf16x8*)(thh + tb + ((size_t)(t + 3) * 4 + kk) * 512 + lane * 8);
        }
        SA += __expf(aA0[0] - 32.f) + __expf(aA0[1] - 32.f) +
              __expf(aA0[2] - 32.f) + __expf(aA0[3] - 32.f) +
              __expf(aA1[0] - 32.f) + __expf(aA1[1] - 32.f) +
              __expf(aA1[2] - 32.f) + __expf(aA1[3] - 32.f);
        SB += __expf(aB0[0] - 32.f) + __expf(aB0[1] - 32.f) +
              __expf(aB0[2] - 32.f) + __expf(aB0[3] - 32.f) +
              __expf(aB1[0] - 32.f) + __expf(aB1[1] - 32.f) +
              __expf(aB1[2] - 32.f) + __expf(aB1[3] - 32.f);
    }
    SA += __shfl_xor(SA, 16, 64); SA += __shfl_xor(SA, 32, 64);
    SB += __shfl_xor(SB, 16, 64); SB += __shfl_xor(SB, 32, 64);
    if (quad == 0) {
        size_t o = ((size_t)(b * NSL + ychunk)) * NS;
        Spart[o + mtA * 16 + l16] = SA;
        Spart[o + (mtA + 1) * 16 + l16] = SB;
    }
}

__global__ void k_combine(const float* __restrict__ Spart, float* __restrict__ wS) {
    int i = blockIdx.x * 256 + threadIdx.x;
    if (i >= B_ * NS) return;
    int b = i / NS, m = i - b * NS;
    float s = 0.f;
#pragma unroll
    for (int sl = 0; sl < NSL; sl++)
        s += Spart[((size_t)(b * NSL + sl)) * NS + m];
    wS[i] = 1.f / s;
}

// ---- g scale into PV-B perm layout ----
__global__ void k_gscale(const float* __restrict__ gcf, const float* __restrict__ wS,
                         short* __restrict__ gc) {
    int i = blockIdx.x * 256 + threadIdx.x;         // B*CI*(NS/8) threads
    int b = i / (CI_ * (NS / 8));
    int rem = i - b * CI_ * (NS / 8);
    int c = rem / (NS / 8);
    int m8 = rem - c * (NS / 8);
    int m = m8 * 8;
    const float* gr = gcf + ((size_t)b * CI_ + c) * NS + m;
    const float* wr = wS + (size_t)b * NS + m;
    short* go = gc + (size_t)b * NS * CI_ + ((size_t)(m8 >> 2) * 8 + (c >> 4)) * 512 +
                (m8 & 3) * 128 + (c & 15) * 8;
#pragma unroll
    for (int j = 0; j < 8; j++) go[j] = f2bf(gr[j] * wr[j]);
}

// ---- PV: wave covers 32n, m-slice x4, fp16 partials, 3-term f; XCD-pinned;
//      cross-iteration phi pipeline (phi(s+1) loads issued after f-phase reads,
//      in flight across mk_pa+y-MFMA+back-edge). grid (1568), block 128 ----
__global__ __launch_bounds__(128, 2) void k_pv(
        const short* __restrict__ thh, const short* __restrict__ thm,
        const short* __restrict__ phh, const short* __restrict__ phm,
        const short* __restrict__ gp, short* __restrict__ part) {
    int wid = threadIdx.x >> 6, lane = threadIdx.x & 63;
    int quad = lane >> 4, l16 = lane & 15;
    int wg = blockIdx.x;
    int pair = wg & 7;                              // (slice, b) -> pins XCD
    int bx = wg >> 3;                               // 0..195
    int slice = pair >> 1, b = pair & 1;
    int ntA = bx * 4 + wid * 2;                     // n-tiles ntA, ntA+1
    size_t tb = (size_t)b * NPIX * CI_, pb = (size_t)b * NS * CI_;
    const short* gpb = gp + (size_t)b * NS * CI_;
    Frag2 afA[4], afB[4];
#pragma unroll
    for (int kk = 0; kk < 4; kk++) {
        afA[kk] = ld2(thh, thm, tb + ((size_t)ntA * 4 + kk) * 512 + lane * 8);
        afB[kk] = ld2(thh, thm, tb + ((size_t)(ntA + 1) * 4 + kk) * 512 + lane * 8);
    }
    f32x4 yaccA[8] = {}, yaccB[8] = {};
    int srcLo = ((2 * quad) & 3) * 16 + l16;
    int srcHi = ((2 * quad + 1) & 3) * 16 + l16;
    bool hiTile = quad >= 2;
    int s_beg = slice * 24 + (slice < 2 ? slice : 2);   // {25,25,24,24} of 98
    int s_end = s_beg + 24 + (slice < 2 ? 1 : 0);
    // phi(s) resident in pc0/pc1 (64 VGPRs)
    Frag2 pc0[4], pc1[4];
#pragma unroll
    for (int kk = 0; kk < 4; kk++) {
        pc0[kk] = ld2(phh, phm, pb + ((size_t)(2 * s_beg) * 4 + kk) * 512 + lane * 8);
        pc1[kk] = ld2(phh, phm, pb + ((size_t)(2 * s_beg + 1) * 4 + kk) * 512 + lane * 8);
    }
    for (int s = s_beg; s < s_end; s++) {
        // g(s): issued at top, consumed at iteration end (~400cy cover)
        bf16x8 gf0 = *(const bf16x8*)(gpb + (size_t)s * 4096 + 0 * 512 + lane * 8);
        bf16x8 gf1 = *(const bf16x8*)(gpb + (size_t)s * 4096 + 1 * 512 + lane * 8);
        bf16x8 gf2 = *(const bf16x8*)(gpb + (size_t)s * 4096 + 2 * 512 + lane * 8);
        bf16x8 gf3 = *(const bf16x8*)(gpb + (size_t)s * 4096 + 3 * 512 + lane * 8);
        bf16x8 gf4 = *(const bf16x8*)(gpb + (size_t)s * 4096 + 4 * 512 + lane * 8);
        bf16x8 gf5 = *(const bf16x8*)(gpb + (size_t)s * 4096 + 5 * 512 + lane * 8);
        bf16x8 gf6 = *(const bf16x8*)(gpb + (size_t)s * 4096 + 6 * 512 + lane * 8);
        bf16x8 gf7 = *(const bf16x8*)(gpb + (size_t)s * 4096 + 7 * 512 + lane * 8);
        f32x4 fA0 = {}, fA1 = {}, fB0 = {}, fB1 = {};
#pragma unroll
        for (int kk = 0; kk < 4; kk++) {
            fA0 = mm3(pc0[kk], afA[kk], fA0);
            fA1 = mm3(pc1[kk], afA[kk], fA1);
            fB0 = mm3(pc0[kk], afB[kk], fB0);
            fB1 = mm3(pc1[kk], afB[kk], fB1);
        }
        // prefetch phi(s+1) — issued after the f-phase reads pc (WAR safe:
        // MFMAs read operands at issue). Benign <=8KB overread on last iter.
#pragma unroll
        for (int kk = 0; kk < 4; kk++) {
            pc0[kk] = ld2(phh, phm, pb + ((size_t)(2 * s + 2) * 4 + kk) * 512 + lane * 8);
            pc1[kk] = ld2(phh, phm, pb + ((size_t)(2 * s + 3) * 4 + kk) * 512 + lane * 8);
        }
        bf16x8 paA = mk_pa(fA0, fA1, srcLo, srcHi, hiTile);
        bf16x8 paB = mk_pa(fB0, fB1, srcLo, srcHi, hiTile);
        yaccA[0] = mfma16(paA, gf0, yaccA[0]); yaccB[0] = mfma16(paB, gf0, yaccB[0]);
        yaccA[1] = mfma16(paA, gf1, yaccA[1]); yaccB[1] = mfma16(paB, gf1, yaccB[1]);
        yaccA[2] = mfma16(paA, gf2, yaccA[2]); yaccB[2] = mfma16(paB, gf2, yaccB[2]);
        yaccA[3] = mfma16(paA, gf3, yaccA[3]); yaccB[3] = mfma16(paB, gf3, yaccB[3]);
        yaccA[4] = mfma16(paA, gf4, yaccA[4]); yaccB[4] = mfma16(paB, gf4, yaccB[4]);
        yaccA[5] = mfma16(paA, gf5, yaccA[5]); yaccB[5] = mfma16(paB, gf5, yaccB[5]);
        yaccA[6] = mfma16(paA, gf6, yaccA[6]); yaccB[6] = mfma16(paB, gf6, yaccB[6]);
        yaccA[7] = mfma16(paA, gf7, yaccA[7]); yaccB[7] = mfma16(paB, gf7, yaccB[7]);
    }
    short* po = part + ((size_t)slice * B_ + b) * NPIX * CI_;
#pragma unroll
    for (int cc = 0; cc < 8; cc++)
#pragma unroll
        for (int r = 0; r < 4; r++) {
            po[pidx(ntA * 16 + quad * 4 + r, cc * 16 + l16)] = f2h(yaccA[cc][r]);
            po[pidx((ntA + 1) * 16 + quad * 4 + r, cc * 16 + l16)] = f2h(yaccB[cc][r]);
        }
}

// ---- combine 4 fp16 y-partials -> 2-plane bf16 (perm order preserved) ----
__global__ void k_ycombine(const short* __restrict__ part, short* __restrict__ yh,
                           short* __restrict__ ym) {
    size_t i = (size_t)blockIdx.x * 256 + threadIdx.x;
    const size_t n = (size_t)B_ * NPIX * CI_;
    if (i >= n) return;
    float v = h2f(part[i]) + h2f(part[n + i]) + h2f(part[2 * n + i]) + h2f(part[3 * n + i]);
    unsigned uh = __float_as_uint(v) & 0xffff0000u;
    yh[i] = (short)(uh >> 16);
    ym[i] = f2bf(v - __uint_as_float(uh));
}

// ---- W conv (3-term, perm y reads) + fused BN stats. grid (NPIX/64, C_/128, B) ----
__global__ __launch_bounds__(256) void k_wconv3(const short* __restrict__ yh,
        const short* __restrict__ ym, const short* __restrict__ WH,
        const short* __restrict__ WM, const float* __restrict__ bias,
        float* __restrict__ Wy, float* __restrict__ stat) {
    int wid = threadIdx.x >> 6, lane = threadIdx.x & 63;
    int quad = lane >> 4, l16 = lane & 15;
    int b = blockIdx.z;
    size_t yb = (size_t)b * NPIX * CI_;
    float* Wyb = Wy + (size_t)b * NPIX * C_;
    int tile = blockIdx.x * 4 + wid;
    int row0 = tile * 16;
    int col0 = blockIdx.y * 128;
    f32x4 acc[8] = {};
#pragma unroll
    for (int kk = 0; kk < 4; kk++) {
        size_t ao = yb + ((size_t)tile * 4 + kk) * 512 + lane * 8;
        bf16x8 ah = *(const bf16x8*)(yh + ao);
        bf16x8 am = *(const bf16x8*)(ym + ao);
#pragma unroll
        for (int cc = 0; cc < 8; cc++) {
            Frag2 w = ld2(WH, WM, (size_t)(col0 + cc * 16 + l16) * CI_ + kk * 32 + quad * 8);
            acc[cc] = mfma16(am, w.h, acc[cc]);
            acc[cc] = mfma16(ah, w.m, acc[cc]);
            acc[cc] = mfma16(ah, w.h, acc[cc]);
        }
    }
#pragma unroll
    for (int cc = 0; cc < 8; cc++) {
        int c = col0 + cc * 16 + l16;
        float bv = bias[c];
        float s1 = 0.f, s2 = 0.f;
#pragma unroll
        for (int r = 0; r < 4; r++) {
            float v = acc[cc][r] + bv;
            Wyb[(size_t)(row0 + quad * 4 + r) * C_ + c] = v;
            s1 += v;
            s2 += v * v;
        }
        s1 += __shfl_xor(s1, 16, 64); s1 += __shfl_xor(s1, 32, 64);
        s2 += __shfl_xor(s2, 16, 64); s2 += __shfl_xor(s2, 32, 64);
        if (quad == 0) {
            atomicAdd(&stat[c], s1);
            atomicAdd(&stat[C_ + c], s2);
        }
    }
}

__global__ void k_bnfin(const float* __restrict__ stat, const float* __restrict__ gamma,
                        const float* __restrict__ beta, float* __restrict__ sc,
                        float* __restrict__ sh) {
    int c = threadIdx.x;
    const float inv = 1.f / (float)(B_ * NPIX);
    float mean = stat[c] * inv;
    float var = stat[C_ + c] * inv - mean * mean;
    float s = gamma[c] * rsqrtf(var + 1e-5f);
    sc[c] = s;
    sh[c] = beta[c] - mean * s;
}

__global__ void k_final(const float* __restrict__ Wy, const float* __restrict__ x,
                        const float* __restrict__ sc, const float* __restrict__ sh,
                        float* __restrict__ out) {
    __shared__ float tile[32][33];
    int b = blockIdx.z;
    const float* Wyb = Wy + (size_t)b * NPIX * C_;
    const float* xb = x + (size_t)b * C_ * NPIX;
    float* ob = out + (size_t)b * C_ * NPIX;
    int p0 = blockIdx.x * 32, c0 = blockIdx.y * 32;
    for (int i = threadIdx.y; i < 32; i += 8)
        tile[i][threadIdx.x] = Wyb[(size_t)(p0 + i) * C_ + c0 + threadIdx.x];
    __syncthreads();
    for (int i = threadIdx.y; i < 32; i += 8) {
        int c = c0 + i;
        size_t o = (size_t)c * NPIX + p0 + threadIdx.x;
        ob[o] = tile[threadIdx.x][i] * sc[c] + sh[c] + xb[o];
    }
}

extern "C" void kernel_launch(void* const* d_in, const int* in_sizes, int n_in,
                              void* d_out, int out_size, void* d_ws, size_t ws_size,
                              hipStream_t stream) {
    (void)in_sizes; (void)n_in; (void)out_size; (void)ws_size;
    const float* x     = (const float*)d_in[0];
    const float* mask  = (const float*)d_in[1];
    const float* g_w   = (const float*)d_in[2];
    const float* g_b   = (const float*)d_in[3];
    const float* th_w  = (const float*)d_in[4];
    const float* th_b  = (const float*)d_in[5];
    const float* ph_w  = (const float*)d_in[6];
    const float* ph_b  = (const float*)d_in[7];
    const float* W_w   = (const float*)d_in[8];
    const float* W_b   = (const float*)d_in[9];
    const float* gamma = (const float*)d_in[10];
    const float* beta  = (const float*)d_in[11];
    float* out = (float*)d_out;

    char* ws = (char*)d_ws;
    // [0, 25.69MB) timeline: A-planes -> {gcf,Spart,wS} -> part (4 slices fp16) -> Wy
    short* AH    = (short*)(ws + 0);              // 12,845,056
    short* AM    = (short*)(ws + 12845056);       // 12,845,056
    float* gcf   = (float*)(ws + 0);              // 3,211,264 (pool -> gscale)
    float* Spart = (float*)(ws + 4194304);        // 702,464 (NSL=28)
    float* wS    = (float*)(ws + 5242880);        // 25,088
    short* part  = (short*)(ws + 0);              // 25,690,112 = 4 x 6,422,528 (fp16)
    float* Wy    = (float*)(ws + 0);              // 25,690,112 (wconv -> final)
    short* thH   = (short*)(ws + 25690112);       // 6,422,528 (perm)
    short* thM   = (short*)(ws + 32112640);       // 6,422,528 (perm)
    short* wwH   = (short*)(ws + 38535168);       // 65,536 x2
    short* wwM   = wwH + 32768;
    float* pfull = (float*)(ws + 44957696);       // 12,845,056 (pre-pool)
    short* yH    = (short*)(ws + 44957696);       // alias after pool (perm)
    short* yM    = (short*)(ws + 51380224);       // (perm)
    short* gfull = (short*)(ws + 57802752);       // 6,422,528
    short* thwH  = (short*)(ws + 64225280);       // weight scratch (dead after convs)
    short* thwM  = thwH + 32768;
    short* thwL  = thwM + 32768;
    short* phwH  = thwL + 32768;
    short* phwM  = phwH + 32768;
    short* phwL  = phwM + 32768;
    short* gwH   = phwL + 32768;
    short* gwM   = gwH + 32768;
    short* ptH   = (short*)(ws + 64225280);       // 1,605,632 (perm, after convs)
    short* ptM   = (short*)(ws + 65830912);       // 1,605,632 (perm)
    short* gc    = (short*)(ws + 69042176);       // 1,605,632 (perm, scaled)
    float* stat  = (float*)(ws + 71099392);       // 2,048
    float* sc    = (float*)(ws + 71101440);       // 1,024
    float* sh    = (float*)(ws + 71102464);       // 1,024

    hipMemsetAsync(stat, 0, 2048, stream);

    k_splitw<<<512, 256, 0, stream>>>(th_w, ph_w, g_w, W_w, thwH, thwM, thwL,
                                      phwH, phwM, phwL, gwH, gwM, wwH, wwM);

    dim3 tb32(32, 8);
    k_transpose2p<<<dim3(NPIX / 32, C_ / 32, B_), tb32, 0, stream>>>(mask, AH, AM);
    k_conv5<<<dim3(NPIX / 32, B_), 128, 0, stream>>>(AH, AM, thwH, thwM, thwL, th_b, thH, thM);

    k_transpose2p<<<dim3(NPIX / 32, C_ / 32, B_), tb32, 0, stream>>>(x, AH, AM);
    k_convxg5<<<dim3(NPIX / 32, B_), 128, 0, stream>>>(AH, AM, phwH, phwM, phwL, gwH, gwM,
                                                       ph_b, g_b, pfull, gfull);

    k_pool<<<dim3(NS * CI_ / 256, B_), 256, 0, stream>>>(pfull, gfull, ptH, ptM, gcf);

    k_stats<<<49 * 56, 128, 0, stream>>>(thH, thM, ptH, ptM, Spart);
    k_combine<<<(B_ * NS + 255) / 256, 256, 0, stream>>>(Spart, wS);
    k_gscale<<<(B_ * CI_ * (NS / 8)) / 256, 256, 0, stream>>>(gcf, wS, gc);

    k_pv<<<196 * 8, 128, 0, stream>>>(thH, thM, ptH, ptM, gc, part);

    k_ycombine<<<(int)(((size_t)B_ * NPIX * CI_ + 255) / 256), 256, 0, stream>>>(part, yH, yM);

    k_wconv3<<<dim3(NPIX / 64, C_ / 128, B_), 256, 0, stream>>>(yH, yM, wwH, wwM, W_b, Wy, stat);
    k_bnfin<<<1, 256, 0, stream>>>(stat, gamma, beta, sc, sh);
    k_final<<<dim3(NPIX / 32, C_ / 32, B_), tb32, 0, stream>>>(Wy, x, sc, sh, out);
}

// Round 9
// 446.960 us; speedup vs baseline: 1.1600x; 1.1600x over previous
//
#include <hip/hip_runtime.h>

// pSGM non-local block, MI355X (round 19: materialized-P softmax).
// r18 falsifier fired: VGPR stayed 100 (compiler collapsed the SW pipeline),
// dur 146->160us. r12-r18 verdict: ~140us is the compiler-idiom floor for the
// recompute-f k_pv (every schedule/MLP/cache lever nulled or regressed).
// r19 changes the ALGORITHM: k_stats already computes exp(f-32) for S -- now it
// also STORES it (bf16, PV-A-frag perm layout; the C-tile->A-frag transpose is
// free through memory). k_pv becomes a pure streaming GEMM y = P @ ghat:
// 10 coalesced loads + 16 mfma per k-step, no exp/shuffle/serial chain.
// P = 157MB < 256MB L3 (written right before read -> L3-resident).
// ws gamble gated on ws_size (need >=229MB); bit-exact r17 fallback otherwise.

#define B_ 2
#define C_ 256
#define CI_ 128
#define NPIX 12544
#define NS 3136
#define NSL 28

typedef short bf16x8 __attribute__((ext_vector_type(8)));
typedef float f32x4 __attribute__((ext_vector_type(4)));

__device__ __forceinline__ short f2bf(float f) {
    unsigned u = __float_as_uint(f);
    u = (u + 0x7fff + ((u >> 16) & 1)) >> 16;   // RNE
    return (short)u;
}
__device__ __forceinline__ float bf2f(short s) {
    return __uint_as_float(((unsigned)(unsigned short)s) << 16);
}
__device__ __forceinline__ short f2h(float f) {
    _Float16 h = (_Float16)f;
    short s;
    __builtin_memcpy(&s, &h, 2);
    return s;
}
__device__ __forceinline__ float h2f(short s) {
    _Float16 h;
    __builtin_memcpy(&h, &s, 2);
    return (float)h;
}
__device__ __forceinline__ f32x4 mfma16(bf16x8 a, bf16x8 b, f32x4 c) {
    return __builtin_amdgcn_mfma_f32_16x16x32_bf16(a, b, c, 0, 0, 0);
}
// perm layout, K=128 operands (theta/phi/g/y): frag-contiguous 1KB wave-loads
__device__ __forceinline__ size_t pidx(int r, int k) {
    return (size_t)((r >> 4) * 4 + (k >> 5)) * 512 +
           (size_t)(((k >> 3) & 3) * 128 + (r & 15) * 8 + (k & 7));
}
// perm layout, K=256 operands (conv A inputs)
__device__ __forceinline__ size_t pidx256(int r, int k) {
    return (size_t)((r >> 4) * 8 + (k >> 5)) * 512 +
           (size_t)(((k >> 3) & 3) * 128 + (r & 15) * 8 + (k & 7));
}

struct Frag3 { bf16x8 h, m, l; };
struct Frag2 { bf16x8 h, m; };

__device__ __forceinline__ Frag3 ld3(const short* __restrict__ h, const short* __restrict__ m,
                                     const short* __restrict__ l, size_t off) {
    Frag3 f;
    f.h = *(const bf16x8*)(h + off);
    f.m = *(const bf16x8*)(m + off);
    f.l = *(const bf16x8*)(l + off);
    return f;
}
__device__ __forceinline__ Frag2 ld2(const short* __restrict__ h, const short* __restrict__ m,
                                     size_t off) {
    Frag2 f;
    f.h = *(const bf16x8*)(h + off);
    f.m = *(const bf16x8*)(m + off);
    return f;
}
// 5-term conv product: A 2-plane (exact to 2^-17) x W 3-plane
__device__ __forceinline__ f32x4 mm5(Frag2 a, Frag3 w, f32x4 acc) {
    acc = mfma16(a.h, w.l, acc);
    acc = mfma16(a.m, w.m, acc);
    acc = mfma16(a.m, w.h, acc);
    acc = mfma16(a.h, w.m, acc);
    acc = mfma16(a.h, w.h, acc);
    return acc;
}
__device__ __forceinline__ f32x4 mm3(Frag2 a, Frag2 b, f32x4 acc) {
    acc = mfma16(a.m, b.h, acc);
    acc = mfma16(a.h, b.m, acc);
    acc = mfma16(a.h, b.h, acc);
    return acc;
}
// 2-term f-emulation: streamed operand h-plane only (drops a_m * b.h term,
// |err| ~ 2^-9*sqrt(128) ~ 0.03 in f) — S denominator AND stored P (consistent)
__device__ __forceinline__ f32x4 mm2s(bf16x8 ah, Frag2 b, f32x4 acc) {
    acc = mfma16(ah, b.m, acc);
    acc = mfma16(ah, b.h, acc);
    return acc;
}
// build PV A-frag from f^T tile pair (fallback path only)
__device__ __forceinline__ bf16x8 mk_pa(f32x4 f0, f32x4 f1, int srcLo, int srcHi, bool hiTile) {
    unsigned t0d0 = (unsigned)(unsigned short)f2bf(__expf(f0[0] - 32.f)) |
                    ((unsigned)(unsigned short)f2bf(__expf(f0[1] - 32.f)) << 16);
    unsigned t0d1 = (unsigned)(unsigned short)f2bf(__expf(f0[2] - 32.f)) |
                    ((unsigned)(unsigned short)f2bf(__expf(f0[3] - 32.f)) << 16);
    unsigned t1d0 = (unsigned)(unsigned short)f2bf(__expf(f1[0] - 32.f)) |
                    ((unsigned)(unsigned short)f2bf(__expf(f1[1] - 32.f)) << 16);
    unsigned t1d1 = (unsigned)(unsigned short)f2bf(__expf(f1[2] - 32.f)) |
                    ((unsigned)(unsigned short)f2bf(__expf(f1[3] - 32.f)) << 16);
    unsigned lo0t0 = __shfl(t0d0, srcLo), lo1t0 = __shfl(t0d1, srcLo);
    unsigned hi0t0 = __shfl(t0d0, srcHi), hi1t0 = __shfl(t0d1, srcHi);
    unsigned lo0t1 = __shfl(t1d0, srcLo), lo1t1 = __shfl(t1d1, srcLo);
    unsigned hi0t1 = __shfl(t1d0, srcHi), hi1t1 = __shfl(t1d1, srcHi);
    unsigned pd[4];
    pd[0] = hiTile ? lo0t1 : lo0t0;
    pd[1] = hiTile ? lo1t1 : lo1t0;
    pd[2] = hiTile ? hi0t1 : hi0t0;
    pd[3] = hiTile ? hi1t1 : hi1t0;
    bf16x8 pa;
    __builtin_memcpy(&pa, pd, 16);
    return pa;
}

// ---- merged weight pre-split: theta/phi 3-plane, g/W 2-plane ----
__global__ void k_splitw(const float* __restrict__ thw, const float* __restrict__ phw,
                         const float* __restrict__ gw, const float* __restrict__ Ww,
                         short* __restrict__ thwH, short* __restrict__ thwM, short* __restrict__ thwL,
                         short* __restrict__ phwH, short* __restrict__ phwM, short* __restrict__ phwL,
                         short* __restrict__ gwH, short* __restrict__ gwM,
                         short* __restrict__ wwH, short* __restrict__ wwM) {
    int i = blockIdx.x * 256 + threadIdx.x;
    int which = i >> 15, j = i & 32767;
    if (which == 0) {
        float x = thw[j];
        unsigned uh = __float_as_uint(x) & 0xffff0000u;
        float r1 = x - __uint_as_float(uh);
        unsigned um = __float_as_uint(r1) & 0xffff0000u;
        thwH[j] = (short)(uh >> 16);
        thwM[j] = (short)(um >> 16);
        thwL[j] = f2bf(r1 - __uint_as_float(um));
    } else if (which == 1) {
        float x = phw[j];
        unsigned uh = __float_as_uint(x) & 0xffff0000u;
        float r1 = x - __uint_as_float(uh);
        unsigned um = __float_as_uint(r1) & 0xffff0000u;
        phwH[j] = (short)(uh >> 16);
        phwM[j] = (short)(um >> 16);
        phwL[j] = f2bf(r1 - __uint_as_float(um));
    } else if (which == 2) {
        float x = gw[j];
        unsigned uh = __float_as_uint(x) & 0xffff0000u;
        gwH[j] = (short)(uh >> 16);
        gwM[j] = f2bf(x - __uint_as_float(uh));
    } else {
        float x = Ww[j];
        unsigned uh = __float_as_uint(x) & 0xffff0000u;
        wwH[j] = (short)(uh >> 16);
        wwM[j] = f2bf(x - __uint_as_float(uh));
    }
}

// ---- transpose + 2-plane split into perm(K=256) ----
__global__ void k_transpose2p(const float* __restrict__ src, short* __restrict__ oh,
                              short* __restrict__ om) {
    __shared__ float tile[32][33];
    int b = blockIdx.z;
    const float* s = src + (size_t)b * C_ * NPIX;
    size_t ob = (size_t)b * NPIX * C_;
    int p0 = blockIdx.x * 32, c0 = blockIdx.y * 32;
    for (int i = threadIdx.y; i < 32; i += 8)
        tile[i][threadIdx.x] = s[(size_t)(c0 + i) * NPIX + p0 + threadIdx.x];
    __syncthreads();
    for (int i = threadIdx.y; i < 32; i += 8) {
        float v = tile[threadIdx.x][i];
        unsigned uh = __float_as_uint(v) & 0xffff0000u;
        size_t o = ob + pidx256(p0 + i, c0 + threadIdx.x);
        oh[o] = (short)(uh >> 16);
        om[o] = f2bf(v - __uint_as_float(uh));
    }
}

// ---- theta conv: 5-term, 2 row-tiles/block. grid (NPIX/32, B), block 128 ----
__global__ __launch_bounds__(128, 2) void k_conv5(const short* __restrict__ AH,
        const short* __restrict__ AM,
        const short* __restrict__ WH, const short* __restrict__ WM, const short* __restrict__ WL,
        const float* __restrict__ bias, short* __restrict__ oh, short* __restrict__ om) {
    int wid = threadIdx.x >> 6, lane = threadIdx.x & 63;
    int quad = lane >> 4, l16 = lane & 15;
    int b = blockIdx.y;
    size_t ab = (size_t)b * NPIX * C_;
    size_t ob = (size_t)b * NPIX * CI_;
    int rt0 = blockIdx.x * 2;
    f32x4 acc[2][4] = {};
    for (int kt = 0; kt < 8; kt++) {
        Frag2 a0 = ld2(AH, AM, ab + ((size_t)rt0 * 8 + kt) * 512 + lane * 8);
        Frag2 a1 = ld2(AH, AM, ab + ((size_t)(rt0 + 1) * 8 + kt) * 512 + lane * 8);
#pragma unroll
        for (int c4 = 0; c4 < 4; c4++) {
            int c = (wid * 4 + c4) * 16 + l16;
            Frag3 w = ld3(WH, WM, WL, (size_t)c * C_ + kt * 32 + quad * 8);
            acc[0][c4] = mm5(a0, w, acc[0][c4]);
            acc[1][c4] = mm5(a1, w, acc[1][c4]);
        }
    }
#pragma unroll
    for (int t2 = 0; t2 < 2; t2++)
#pragma unroll
        for (int c4 = 0; c4 < 4; c4++) {
            int c = (wid * 4 + c4) * 16 + l16;
            float bv = bias[c];
#pragma unroll
            for (int r = 0; r < 4; r++) {
                float v = acc[t2][c4][r] + bv;
                unsigned uh = __float_as_uint(v) & 0xffff0000u;
                size_t o = ob + pidx((rt0 + t2) * 16 + quad * 4 + r, c);
                oh[o] = (short)(uh >> 16);
                om[o] = f2bf(v - __uint_as_float(uh));
            }
        }
}

// ---- fused phi(5-term->fp32) + g(3-term->bf16), 2 row-tiles/block ----
__global__ __launch_bounds__(128, 2) void k_convxg5(const short* __restrict__ AH,
        const short* __restrict__ AM,
        const short* __restrict__ PH, const short* __restrict__ PM, const short* __restrict__ PL,
        const short* __restrict__ GH, const short* __restrict__ GM,
        const float* __restrict__ pbias, const float* __restrict__ gbias,
        float* __restrict__ pfull, short* __restrict__ gout) {
    int wid = threadIdx.x >> 6, lane = threadIdx.x & 63;
    int quad = lane >> 4, l16 = lane & 15;
    int b = blockIdx.y;
    size_t ab = (size_t)b * NPIX * C_;
    float* Pb = pfull + (size_t)b * NPIX * CI_;
    short* Gb = gout + (size_t)b * NPIX * CI_;
    int rt0 = blockIdx.x * 2;
    f32x4 accp[2][4] = {}, accg[2][4] = {};
    for (int kt = 0; kt < 8; kt++) {
        Frag2 a0 = ld2(AH, AM, ab + ((size_t)rt0 * 8 + kt) * 512 + lane * 8);
        Frag2 a1 = ld2(AH, AM, ab + ((size_t)(rt0 + 1) * 8 + kt) * 512 + lane * 8);
#pragma unroll
        for (int c4 = 0; c4 < 4; c4++) {
            int c = (wid * 4 + c4) * 16 + l16;
            size_t wo = (size_t)c * C_ + kt * 32 + quad * 8;
            Frag3 wp = ld3(PH, PM, PL, wo);
            accp[0][c4] = mm5(a0, wp, accp[0][c4]);
            accp[1][c4] = mm5(a1, wp, accp[1][c4]);
            Frag2 wg = ld2(GH, GM, wo);
            accg[0][c4] = mm3(a0, wg, accg[0][c4]);
            accg[1][c4] = mm3(a1, wg, accg[1][c4]);
        }
    }
#pragma unroll
    for (int t2 = 0; t2 < 2; t2++)
#pragma unroll
        for (int c4 = 0; c4 < 4; c4++) {
            int c = (wid * 4 + c4) * 16 + l16;
            float pbv = pbias[c], gbv = gbias[c];
#pragma unroll
            for (int r = 0; r < 4; r++) {
                size_t o = (size_t)((rt0 + t2) * 16 + quad * 4 + r) * CI_ + c;
                Pb[o] = accp[t2][c4][r] + pbv;
                Gb[o] = f2bf(accg[t2][c4][r] + gbv);
            }
        }
}

// ---- pool: pfull fp32 -> phi 2-plane PERM; gfull bf16 -> gcf fp32 (ci, m) ----
__global__ void k_pool(const float* __restrict__ pfull, const short* __restrict__ gfull,
                       short* __restrict__ pth, short* __restrict__ ptm,
                       float* __restrict__ gcf) {
    int b = blockIdx.y;
    int idx = blockIdx.x * 256 + threadIdx.x;       // idx = m*128 + ci
    int ci = idx & 127, m = idx >> 7;
    int t = m / 196, r2i = m - t * 196;
    int h2 = r2i / 14, w2 = r2i - h2 * 14;
    size_t p = (size_t)t * 784 + (size_t)(2 * h2) * 28 + 2 * w2;
    size_t i0 = (size_t)b * NPIX * CI_ + p * CI_ + ci;
    float pv = fmaxf(fmaxf(pfull[i0], pfull[i0 + CI_]),
                     fmaxf(pfull[i0 + 28 * CI_], pfull[i0 + 29 * CI_]));
    unsigned uh = __float_as_uint(pv) & 0xffff0000u;
    size_t ob = (size_t)b * NS * CI_ + pidx(m, ci);
    pth[ob] = (short)(uh >> 16);
    ptm[ob] = f2bf(pv - __uint_as_float(uh));
    float g0 = fmaxf(fmaxf(bf2f(gfull[i0]), bf2f(gfull[i0 + CI_])),
                     fmaxf(bf2f(gfull[i0 + 28 * CI_]), bf2f(gfull[i0 + 29 * CI_])));
    gcf[(size_t)b * NS * CI_ + (size_t)ci * NS + m] = g0;
}

// ---- stats+P: S[m]=sum_n exp(f-32) AND store P=exp(f-32) bf16 in PV-A perm.
//      XCD-pinned wgid = (tchunk*2+b) + 56*x. grid (49*56), block 128 ----
__global__ __launch_bounds__(128, 2) void k_statsP(
        const short* __restrict__ thh, const short* __restrict__ phh,
        const short* __restrict__ phm, float* __restrict__ Spart,
        short* __restrict__ Pbuf) {
    int wid = threadIdx.x >> 6, lane = threadIdx.x & 63;
    int quad = lane >> 4, l16 = lane & 15;
    int wg = blockIdx.x;
    int p = wg % 56;
    int bx = wg / 56;
    int b = p & 1, ychunk = p >> 1;
    size_t tb = (size_t)b * NPIX * CI_, pb = (size_t)b * NS * CI_;
    short* PB = Pbuf + (size_t)b * NPIX * NS;
    int mtA = bx * 4 + wid * 2;                     // m-tiles mtA (even), mtA+1
    Frag2 bfA[4], bfB[4];
#pragma unroll
    for (int kk = 0; kk < 4; kk++) {
        bfA[kk] = ld2(phh, phm, pb + ((size_t)mtA * 4 + kk) * 512 + lane * 8);
        bfB[kk] = ld2(phh, phm, pb + ((size_t)(mtA + 1) * 4 + kk) * 512 + lane * 8);
    }
    float SA = 0.f, SB = 0.f;
    int t_beg = ychunk * (784 / NSL), t_end = t_beg + 784 / NSL;
    int kg = mtA >> 1;                              // 32-m group index of P
    // lane's scatter base within a C-tile: subk*128 + (quad*4+r)*8 + (m&7)
    size_t laneoff = (size_t)(l16 >> 3) * 128 + (l16 & 7) + (size_t)quad * 32;
    for (int t = t_beg; t < t_end; t += 2) {
        f32x4 aA0 = {}, aA1 = {}, aB0 = {}, aB1 = {};
#pragma unroll
        for (int kk = 0; kk < 4; kk++) {
            bf16x8 x0 = *(const bf16x8*)(thh + tb + ((size_t)t * 4 + kk) * 512 + lane * 8);
            bf16x8 x1 = *(const bf16x8*)(thh + tb + ((size_t)(t + 1) * 4 + kk) * 512 + lane * 8);
            aA0 = mm2s(x0, bfA[kk], aA0);
            aA1 = mm2s(x1, bfA[kk], aA1);
            aB0 = mm2s(x0, bfB[kk], aB0);
            aB1 = mm2s(x1, bfB[kk], aB1);
        }
        size_t cA0 = ((size_t)t * 98 + kg) * 512 + laneoff;         // tile (t, mtA)
        size_t cA1 = cA0 + 98 * 512;                                // (t+1, mtA)
        size_t cB0 = cA0 + 256;                                     // (t, mtA+1)
        size_t cB1 = cA1 + 256;                                     // (t+1, mtA+1)
#pragma unroll
        for (int r = 0; r < 4; r++) {
            float eA0 = __expf(aA0[r] - 32.f); SA += eA0; PB[cA0 + r * 8] = f2bf(eA0);
            float eA1 = __expf(aA1[r] - 32.f); SA += eA1; PB[cA1 + r * 8] = f2bf(eA1);
            float eB0 = __expf(aB0[r] - 32.f); SB += eB0; PB[cB0 + r * 8] = f2bf(eB0);
            float eB1 = __expf(aB1[r] - 32.f); SB += eB1; PB[cB1 + r * 8] = f2bf(eB1);
        }
    }
    SA += __shfl_xor(SA, 16, 64); SA += __shfl_xor(SA, 32, 64);
    SB += __shfl_xor(SB, 16, 64); SB += __shfl_xor(SB, 32, 64);
    if (quad == 0) {
        size_t o = ((size_t)(b * NSL + ychunk)) * NS;
        Spart[o + mtA * 16 + l16] = SA;
        Spart[o + (mtA + 1) * 16 + l16] = SB;
    }
}

// ---- fallback stats (no P store) — r17 verified ----
__global__ __launch_bounds__(128, 2) void k_stats(
        const short* __restrict__ thh, const short* __restrict__ phh,
        const short* __restrict__ phm, float* __restrict__ Spart) {
    int wid = threadIdx.x >> 6, lane = threadIdx.x & 63;
    int quad = lane >> 4, l16 = lane & 15;
    int wg = blockIdx.x;
    int p = wg % 56;
    int bx = wg / 56;
    int b = p & 1, ychunk = p >> 1;
    size_t tb = (size_t)b * NPIX * CI_, pb = (size_t)b * NS * CI_;
    int mtA = bx * 4 + wid * 2;
    Frag2 bfA[4], bfB[4];
#pragma unroll
    for (int kk = 0; kk < 4; kk++) {
        bfA[kk] = ld2(phh, phm, pb + ((size_t)mtA * 4 + kk) * 512 + lane * 8);
        bfB[kk] = ld2(phh, phm, pb + ((size_t)(mtA + 1) * 4 + kk) * 512 + lane * 8);
    }
    float SA = 0.f, SB = 0.f;
    int t_beg = ychunk * (784 / NSL), t_end = t_beg + 784 / NSL;
    for (int t = t_beg; t < t_end; t += 2) {
        f32x4 aA0 = {}, aA1 = {}, aB0 = {}, aB1 = {};
#pragma unroll
        for (int kk = 0; kk < 4; kk++) {
            bf16x8 x0 = *(const bf16x8*)(thh + tb + ((size_t)t * 4 + kk) * 512 + lane * 8);
            bf16x8 x1 = *(const bf16x8*)(thh + tb + ((size_t)(t + 1) * 4 + kk) * 512 + lane * 8);
            aA0 = mm2s(x0, bfA[kk], aA0);
            aA1 = mm2s(x1, bfA[kk], aA1);
            aB0 = mm2s(x0, bfB[kk], aB0);
            aB1 = mm2s(x1, bfB[kk], aB1);
        }
        SA += __expf(aA0[0] - 32.f) + __expf(aA0[1] - 32.f) +
              __expf(aA0[2] - 32.f) + __expf(aA0[3] - 32.f) +
              __expf(aA1[0] - 32.f) + __expf(aA1[1] - 32.f) +
              __expf(aA1[2] - 32.f) + __expf(aA1[3] - 32.f);
        SB += __expf(aB0[0] - 32.f) + __expf(aB0[1] - 32.f) +
              __expf(aB0[2] - 32.f) + __expf(aB0[3] - 32.f) +
              __expf(aB1[0] - 32.f) + __expf(aB1[1] - 32.f) +
              __expf(aB1[2] - 32.f) + __expf(aB1[3] - 32.f);
    }
    SA += __shfl_xor(SA, 16, 64); SA += __shfl_xor(SA, 32, 64);
    SB += __shfl_xor(SB, 16, 64); SB += __shfl_xor(SB, 32, 64);
    if (quad == 0) {
        size_t o = ((size_t)(b * NSL + ychunk)) * NS;
        Spart[o + mtA * 16 + l16] = SA;
        Spart[o + (mtA + 1) * 16 + l16] = SB;
    }
}

__global__ void k_combine(const float* __restrict__ Spart, float* __restrict__ wS) {
    int i = blockIdx.x * 256 + threadIdx.x;
    if (i >= B_ * NS) return;
    int b = i / NS, m = i - b * NS;
    float s = 0.f;
#pragma unroll
    for (int sl = 0; sl < NSL; sl++)
        s += Spart[((size_t)(b * NSL + sl)) * NS + m];
    wS[i] = 1.f / s;
}

// ---- g scale into PV-B perm layout ----
__global__ void k_gscale(const float* __restrict__ gcf, const float* __restrict__ wS,
                         short* __restrict__ gc) {
    int i = blockIdx.x * 256 + threadIdx.x;         // B*CI*(NS/8) threads
    int b = i / (CI_ * (NS / 8));
    int rem = i - b * CI_ * (NS / 8);
    int c = rem / (NS / 8);
    int m8 = rem - c * (NS / 8);
    int m = m8 * 8;
    const float* gr = gcf + ((size_t)b * CI_ + c) * NS + m;
    const float* wr = wS + (size_t)b * NS + m;
    short* go = gc + (size_t)b * NS * CI_ + ((size_t)(m8 >> 2) * 8 + (c >> 4)) * 512 +
                (m8 & 3) * 128 + (c & 15) * 8;
#pragma unroll
    for (int j = 0; j < 8; j++) go[j] = f2bf(gr[j] * wr[j]);
}

// ---- PV-GEMM: y = P @ ghat. Wave: 2 n-tiles, m-slice x4, fp16 partials.
//      Per k-step: 2 A-frag + 8 B-frag loads, 16 mfma. XCD-pinned.
//      grid (1568), block 128 ----
__global__ __launch_bounds__(128, 2) void k_pvP(
        const short* __restrict__ Pbuf, const short* __restrict__ gp,
        short* __restrict__ part) {
    int wid = threadIdx.x >> 6, lane = threadIdx.x & 63;
    int quad = lane >> 4, l16 = lane & 15;
    int wg = blockIdx.x;
    int pair = wg & 7;                              // (slice, b) -> pins XCD
    int bx = wg >> 3;                               // 0..195
    int slice = pair >> 1, b = pair & 1;
    int ntA = bx * 4 + wid * 2;                     // n-tiles ntA, ntA+1
    const short* PB = Pbuf + (size_t)b * NPIX * NS;
    const short* gpb = gp + (size_t)b * NS * CI_;
    f32x4 yaccA[8] = {}, yaccB[8] = {};
    int s_beg = slice * 24 + (slice < 2 ? slice : 2);   // {25,25,24,24} of 98
    int s_end = s_beg + 24 + (slice < 2 ? 1 : 0);
    const short* pA = PB + ((size_t)ntA * 98 + s_beg) * 512 + lane * 8;
    const short* pBp = PB + ((size_t)(ntA + 1) * 98 + s_beg) * 512 + lane * 8;
    const short* gb = gpb + (size_t)s_beg * 4096 + lane * 8;
#pragma unroll 2
    for (int s = s_beg; s < s_end; s++) {
        bf16x8 pa0 = *(const bf16x8*)pA;
        bf16x8 pa1 = *(const bf16x8*)pBp;
        bf16x8 g0 = *(const bf16x8*)(gb + 0 * 512);
        bf16x8 g1 = *(const bf16x8*)(gb + 1 * 512);
        bf16x8 g2 = *(const bf16x8*)(gb + 2 * 512);
        bf16x8 g3 = *(const bf16x8*)(gb + 3 * 512);
        bf16x8 g4 = *(const bf16x8*)(gb + 4 * 512);
        bf16x8 g5 = *(const bf16x8*)(gb + 5 * 512);
        bf16x8 g6 = *(const bf16x8*)(gb + 6 * 512);
        bf16x8 g7 = *(const bf16x8*)(gb + 7 * 512);
        pA += 512; pBp += 512; gb += 4096;
        yaccA[0] = mfma16(pa0, g0, yaccA[0]); yaccB[0] = mfma16(pa1, g0, yaccB[0]);
        yaccA[1] = mfma16(pa0, g1, yaccA[1]); yaccB[1] = mfma16(pa1, g1, yaccB[1]);
        yaccA[2] = mfma16(pa0, g2, yaccA[2]); yaccB[2] = mfma16(pa1, g2, yaccB[2]);
        yaccA[3] = mfma16(pa0, g3, yaccA[3]); yaccB[3] = mfma16(pa1, g3, yaccB[3]);
        yaccA[4] = mfma16(pa0, g4, yaccA[4]); yaccB[4] = mfma16(pa1, g4, yaccB[4]);
        yaccA[5] = mfma16(pa0, g5, yaccA[5]); yaccB[5] = mfma16(pa1, g5, yaccB[5]);
        yaccA[6] = mfma16(pa0, g6, yaccA[6]); yaccB[6] = mfma16(pa1, g6, yaccB[6]);
        yaccA[7] = mfma16(pa0, g7, yaccA[7]); yaccB[7] = mfma16(pa1, g7, yaccB[7]);
    }
    short* po = part + ((size_t)slice * B_ + b) * NPIX * CI_;
#pragma unroll
    for (int cc = 0; cc < 8; cc++)
#pragma unroll
        for (int r = 0; r < 4; r++) {
            po[pidx(ntA * 16 + quad * 4 + r, cc * 16 + l16)] = f2h(yaccA[cc][r]);
            po[pidx((ntA + 1) * 16 + quad * 4 + r, cc * 16 + l16)] = f2h(yaccB[cc][r]);
        }
}

// ---- fallback PV (recompute-f) — r17 verified ----
__global__ __launch_bounds__(128, 2) void k_pv(
        const short* __restrict__ thh, const short* __restrict__ thm,
        const short* __restrict__ phh, const short* __restrict__ phm,
        const short* __restrict__ gp, short* __restrict__ part) {
    int wid = threadIdx.x >> 6, lane = threadIdx.x & 63;
    int quad = lane >> 4, l16 = lane & 15;
    int wg = blockIdx.x;
    int pair = wg & 7;
    int bx = wg >> 3;
    int slice = pair >> 1, b = pair & 1;
    int ntA = bx * 4 + wid * 2;
    size_t tb = (size_t)b * NPIX * CI_, pb = (size_t)b * NS * CI_;
    const short* gpb = gp + (size_t)b * NS * CI_;
    Frag2 afA[4], afB[4];
#pragma unroll
    for (int kk = 0; kk < 4; kk++) {
        afA[kk] = ld2(thh, thm, tb + ((size_t)ntA * 4 + kk) * 512 + lane * 8);
        afB[kk] = ld2(thh, thm, tb + ((size_t)(ntA + 1) * 4 + kk) * 512 + lane * 8);
    }
    f32x4 yaccA[8] = {}, yaccB[8] = {};
    int srcLo = ((2 * quad) & 3) * 16 + l16;
    int srcHi = ((2 * quad + 1) & 3) * 16 + l16;
    bool hiTile = quad >= 2;
    int s_beg = slice * 24 + (slice < 2 ? slice : 2);
    int s_end = s_beg + 24 + (slice < 2 ? 1 : 0);
    for (int s = s_beg; s < s_end; s++) {
        bf16x8 gf0 = *(const bf16x8*)(gpb + (size_t)s * 4096 + 0 * 512 + lane * 8);
        bf16x8 gf1 = *(const bf16x8*)(gpb + (size_t)s * 4096 + 1 * 512 + lane * 8);
        bf16x8 gf2 = *(const bf16x8*)(gpb + (size_t)s * 4096 + 2 * 512 + lane * 8);
        bf16x8 gf3 = *(const bf16x8*)(gpb + (size_t)s * 4096 + 3 * 512 + lane * 8);
        bf16x8 gf4 = *(const bf16x8*)(gpb + (size_t)s * 4096 + 4 * 512 + lane * 8);
        bf16x8 gf5 = *(const bf16x8*)(gpb + (size_t)s * 4096 + 5 * 512 + lane * 8);
        bf16x8 gf6 = *(const bf16x8*)(gpb + (size_t)s * 4096 + 6 * 512 + lane * 8);
        bf16x8 gf7 = *(const bf16x8*)(gpb + (size_t)s * 4096 + 7 * 512 + lane * 8);
        f32x4 fA0 = {}, fA1 = {}, fB0 = {}, fB1 = {};
#pragma unroll
        for (int kk = 0; kk < 4; kk++) {
            Frag2 p0 = ld2(phh, phm, pb + ((size_t)(2 * s) * 4 + kk) * 512 + lane * 8);
            Frag2 p1 = ld2(phh, phm, pb + ((size_t)(2 * s + 1) * 4 + kk) * 512 + lane * 8);
            fA0 = mm3(p0, afA[kk], fA0);
            fA1 = mm3(p1, afA[kk], fA1);
            fB0 = mm3(p0, afB[kk], fB0);
            fB1 = mm3(p1, afB[kk], fB1);
        }
        bf16x8 paA = mk_pa(fA0, fA1, srcLo, srcHi, hiTile);
        bf16x8 paB = mk_pa(fB0, fB1, srcLo, srcHi, hiTile);
        yaccA[0] = mfma16(paA, gf0, yaccA[0]); yaccB[0] = mfma16(paB, gf0, yaccB[0]);
        yaccA[1] = mfma16(paA, gf1, yaccA[1]); yaccB[1] = mfma16(paB, gf1, yaccB[1]);
        yaccA[2] = mfma16(paA, gf2, yaccA[2]); yaccB[2] = mfma16(paB, gf2, yaccB[2]);
        yaccA[3] = mfma16(paA, gf3, yaccA[3]); yaccB[3] = mfma16(paB, gf3, yaccB[3]);
        yaccA[4] = mfma16(paA, gf4, yaccA[4]); yaccB[4] = mfma16(paB, gf4, yaccB[4]);
        yaccA[5] = mfma16(paA, gf5, yaccA[5]); yaccB[5] = mfma16(paB, gf5, yaccB[5]);
        yaccA[6] = mfma16(paA, gf6, yaccA[6]); yaccB[6] = mfma16(paB, gf6, yaccB[6]);
        yaccA[7] = mfma16(paA, gf7, yaccA[7]); yaccB[7] = mfma16(paB, gf7, yaccB[7]);
    }
    short* po = part + ((size_t)slice * B_ + b) * NPIX * CI_;
#pragma unroll
    for (int cc = 0; cc < 8; cc++)
#pragma unroll
        for (int r = 0; r < 4; r++) {
            po[pidx(ntA * 16 + quad * 4 + r, cc * 16 + l16)] = f2h(yaccA[cc][r]);
            po[pidx((ntA + 1) * 16 + quad * 4 + r, cc * 16 + l16)] = f2h(yaccB[cc][r]);
        }
}

// ---- combine 4 fp16 y-partials -> 2-plane bf16 (perm order preserved) ----
__global__ void k_ycombine(const short* __restrict__ part, short* __restrict__ yh,
                           short* __restrict__ ym) {
    size_t i = (size_t)blockIdx.x * 256 + threadIdx.x;
    const size_t n = (size_t)B_ * NPIX * CI_;
    if (i >= n) return;
    float v = h2f(part[i]) + h2f(part[n + i]) + h2f(part[2 * n + i]) + h2f(part[3 * n + i]);
    unsigned uh = __float_as_uint(v) & 0xffff0000u;
    yh[i] = (short)(uh >> 16);
    ym[i] = f2bf(v - __uint_as_float(uh));
}

// ---- W conv (3-term, perm y reads) + fused BN stats. grid (NPIX/64, C_/128, B) ----
__global__ __launch_bounds__(256) void k_wconv3(const short* __restrict__ yh,
        const short* __restrict__ ym, const short* __restrict__ WH,
        const short* __restrict__ WM, const float* __restrict__ bias,
        float* __restrict__ Wy, float* __restrict__ stat) {
    int wid = threadIdx.x >> 6, lane = threadIdx.x & 63;
    int quad = lane >> 4, l16 = lane & 15;
    int b = blockIdx.z;
    size_t yb = (size_t)b * NPIX * CI_;
    float* Wyb = Wy + (size_t)b * NPIX * C_;
    int tile = blockIdx.x * 4 + wid;
    int row0 = tile * 16;
    int col0 = blockIdx.y * 128;
    f32x4 acc[8] = {};
#pragma unroll
    for (int kk = 0; kk < 4; kk++) {
        size_t ao = yb + ((size_t)tile * 4 + kk) * 512 + lane * 8;
        bf16x8 ah = *(const bf16x8*)(yh + ao);
        bf16x8 am = *(const bf16x8*)(ym + ao);
#pragma unroll
        for (int cc = 0; cc < 8; cc++) {
            Frag2 w = ld2(WH, WM, (size_t)(col0 + cc * 16 + l16) * CI_ + kk * 32 + quad * 8);
            acc[cc] = mfma16(am, w.h, acc[cc]);
            acc[cc] = mfma16(ah, w.m, acc[cc]);
            acc[cc] = mfma16(ah, w.h, acc[cc]);
        }
    }
#pragma unroll
    for (int cc = 0; cc < 8; cc++) {
        int c = col0 + cc * 16 + l16;
        float bv = bias[c];
        float s1 = 0.f, s2 = 0.f;
#pragma unroll
        for (int r = 0; r < 4; r++) {
            float v = acc[cc][r] + bv;
            Wyb[(size_t)(row0 + quad * 4 + r) * C_ + c] = v;
            s1 += v;
            s2 += v * v;
        }
        s1 += __shfl_xor(s1, 16, 64); s1 += __shfl_xor(s1, 32, 64);
        s2 += __shfl_xor(s2, 16, 64); s2 += __shfl_xor(s2, 32, 64);
        if (quad == 0) {
            atomicAdd(&stat[c], s1);
            atomicAdd(&stat[C_ + c], s2);
        }
    }
}

__global__ void k_bnfin(const float* __restrict__ stat, const float* __restrict__ gamma,
                        const float* __restrict__ beta, float* __restrict__ sc,
                        float* __restrict__ sh) {
    int c = threadIdx.x;
    const float inv = 1.f / (float)(B_ * NPIX);
    float mean = stat[c] * inv;
    float var = stat[C_ + c] * inv - mean * mean;
    float s = gamma[c] * rsqrtf(var + 1e-5f);
    sc[c] = s;
    sh[c] = beta[c] - mean * s;
}

__global__ void k_final(const float* __restrict__ Wy, const float* __restrict__ x,
                        const float* __restrict__ sc, const float* __restrict__ sh,
                        float* __restrict__ out) {
    __shared__ float tile[32][33];
    int b = blockIdx.z;
    const float* Wyb = Wy + (size_t)b * NPIX * C_;
    const float* xb = x + (size_t)b * C_ * NPIX;
    float* ob = out + (size_t)b * C_ * NPIX;
    int p0 = blockIdx.x * 32, c0 = blockIdx.y * 32;
    for (int i = threadIdx.y; i < 32; i += 8)
        tile[i][threadIdx.x] = Wyb[(size_t)(p0 + i) * C_ + c0 + threadIdx.x];
    __syncthreads();
    for (int i = threadIdx.y; i < 32; i += 8) {
        int c = c0 + i;
        size_t o = (size_t)c * NPIX + p0 + threadIdx.x;
        ob[o] = tile[threadIdx.x][i] * sc[c] + sh[c] + xb[o];
    }
}

extern "C" void kernel_launch(void* const* d_in, const int* in_sizes, int n_in,
                              void* d_out, int out_size, void* d_ws, size_t ws_size,
                              hipStream_t stream) {
    (void)in_sizes; (void)n_in; (void)out_size;
    const float* x     = (const float*)d_in[0];
    const float* mask  = (const float*)d_in[1];
    const float* g_w   = (const float*)d_in[2];
    const float* g_b   = (const float*)d_in[3];
    const float* th_w  = (const float*)d_in[4];
    const float* th_b  = (const float*)d_in[5];
    const float* ph_w  = (const float*)d_in[6];
    const float* ph_b  = (const float*)d_in[7];
    const float* W_w   = (const float*)d_in[8];
    const float* W_b   = (const float*)d_in[9];
    const float* gamma = (const float*)d_in[10];
    const float* beta  = (const float*)d_in[11];
    float* out = (float*)d_out;

    char* ws = (char*)d_ws;
    // [0, 25.69MB) timeline: A-planes -> {gcf,Spart,wS} -> part (4 slices fp16) -> Wy
    short* AH    = (short*)(ws + 0);              // 12,845,056
    short* AM    = (short*)(ws + 12845056);       // 12,845,056
    float* gcf   = (float*)(ws + 0);              // 3,211,264 (pool -> gscale)
    float* Spart = (float*)(ws + 4194304);        // 702,464 (NSL=28)
    float* wS    = (float*)(ws + 5242880);        // 25,088
    short* part  = (short*)(ws + 0);              // 25,690,112 = 4 x 6,422,528 (fp16)
    float* Wy    = (float*)(ws + 0);              // 25,690,112 (wconv -> final)
    short* thH   = (short*)(ws + 25690112);       // 6,422,528 (perm)
    short* thM   = (short*)(ws + 32112640);       // 6,422,528 (perm)
    short* wwH   = (short*)(ws + 38535168);       // 65,536 x2
    short* wwM   = wwH + 32768;
    float* pfull = (float*)(ws + 44957696);       // 12,845,056 (pre-pool)
    short* yH    = (short*)(ws + 44957696);       // alias after pool (perm)
    short* yM    = (short*)(ws + 51380224);       // (perm)
    short* gfull = (short*)(ws + 57802752);       // 6,422,528
    short* thwH  = (short*)(ws + 64225280);       // weight scratch (dead after convs)
    short* thwM  = thwH + 32768;
    short* thwL  = thwM + 32768;
    short* phwH  = thwL + 32768;
    short* phwM  = phwH + 32768;
    short* phwL  = phwM + 32768;
    short* gwH   = phwL + 32768;
    short* gwM   = gwH + 32768;
    short* ptH   = (short*)(ws + 64225280);       // 1,605,632 (perm, after convs)
    short* ptM   = (short*)(ws + 65830912);       // 1,605,632 (perm)
    short* gc    = (short*)(ws + 69042176);       // 1,605,632 (perm, scaled)
    float* stat  = (float*)(ws + 71099392);       // 2,048
    float* sc    = (float*)(ws + 71101440);       // 1,024
    float* sh    = (float*)(ws + 71102464);       // 1,024
    // P buffer (bf16, PV-A perm): [71303168, 228655104) — gated on ws_size
    const size_t pOff = 71303168ull;
    const size_t pBytes = (size_t)B_ * NPIX * NS * sizeof(short);   // 157,351,936
    bool bigws = ws_size >= pOff + pBytes;
    short* Pbuf = (short*)(ws + pOff);

    hipMemsetAsync(stat, 0, 2048, stream);

    k_splitw<<<512, 256, 0, stream>>>(th_w, ph_w, g_w, W_w, thwH, thwM, thwL,
                                      phwH, phwM, phwL, gwH, gwM, wwH, wwM);

    dim3 tb32(32, 8);
    k_transpose2p<<<dim3(NPIX / 32, C_ / 32, B_), tb32, 0, stream>>>(mask, AH, AM);
    k_conv5<<<dim3(NPIX / 32, B_), 128, 0, stream>>>(AH, AM, thwH, thwM, thwL, th_b, thH, thM);

    k_transpose2p<<<dim3(NPIX / 32, C_ / 32, B_), tb32, 0, stream>>>(x, AH, AM);
    k_convxg5<<<dim3(NPIX / 32, B_), 128, 0, stream>>>(AH, AM, phwH, phwM, phwL, gwH, gwM,
                                                       ph_b, g_b, pfull, gfull);

    k_pool<<<dim3(NS * CI_ / 256, B_), 256, 0, stream>>>(pfull, gfull, ptH, ptM, gcf);

    if (bigws)
        k_statsP<<<49 * 56, 128, 0, stream>>>(thH, ptH, ptM, Spart, Pbuf);
    else
        k_stats<<<49 * 56, 128, 0, stream>>>(thH, ptH, ptM, Spart);
    k_combine<<<(B_ * NS + 255) / 256, 256, 0, stream>>>(Spart, wS);
    k_gscale<<<(B_ * CI_ * (NS / 8)) / 256, 256, 0, stream>>>(gcf, wS, gc);

    if (bigws)
        k_pvP<<<196 * 8, 128, 0, stream>>>(Pbuf, gc, part);
    else
        k_pv<<<196 * 8, 128, 0, stream>>>(thH, thM, ptH, ptM, gc, part);

    k_ycombine<<<(int)(((size_t)B_ * NPIX * CI_ + 255) / 256), 256, 0, stream>>>(part, yH, yM);

    k_wconv3<<<dim3(NPIX / 64, C_ / 128, B_), 256, 0, stream>>>(yH, yM, wwH, wwM, W_b, Wy, stat);
    k_bnfin<<<1, 256, 0, stream>>>(stat, gamma, beta, sc, sh);
    k_final<<<dim3(NPIX / 32, C_ / 32, B_), tb32, 0, stream>>>(Wy, x, sc, sh, out);
}

// Round 10
// 404.414 us; speedup vs baseline: 1.2820x; 1.1052x over previous
//
#include <hip/hip_runtime.h>

// pSGM non-local block, MI355X (round 20: de-atomize k_wconv3 BN stats).
// r19 WIN (529->447, absmax 1.0): P materialized in k_statsP (PV-A perm),
// k_pvP = pure streaming GEMM. Exposed k_wconv3 = 93us @ MfmaUtil 1.9 /
// VALU 1.7 / HBM 5.6% — all pipes idle. Compulsory traffic ~40MB, per-wave
// work ~us. Pathology: ~800K lane-atomicAdds onto 2KB stat (1568 serialized
// same-address RMWs, ~32 L2 lines) -> waves park at end-of-kernel vmcnt(0)
// while the L2 atomic queue drains. r20: LDS cross-wave reduce (4KB) + one
// 1KB partial store/block into pstat[784][256] (aliases dead ptH region);
// k_bnfin does the 392-way partial reduction. Falsifier: if wconv3 stays
// ~90us, atomics exonerated -> next suspect scattered fp32 Wy stores.

#define B_ 2
#define C_ 256
#define CI_ 128
#define NPIX 12544
#define NS 3136
#define NSL 28

typedef short bf16x8 __attribute__((ext_vector_type(8)));
typedef float f32x4 __attribute__((ext_vector_type(4)));

__device__ __forceinline__ short f2bf(float f) {
    unsigned u = __float_as_uint(f);
    u = (u + 0x7fff + ((u >> 16) & 1)) >> 16;   // RNE
    return (short)u;
}
__device__ __forceinline__ float bf2f(short s) {
    return __uint_as_float(((unsigned)(unsigned short)s) << 16);
}
__device__ __forceinline__ short f2h(float f) {
    _Float16 h = (_Float16)f;
    short s;
    __builtin_memcpy(&s, &h, 2);
    return s;
}
__device__ __forceinline__ float h2f(short s) {
    _Float16 h;
    __builtin_memcpy(&h, &s, 2);
    return (float)h;
}
__device__ __forceinline__ f32x4 mfma16(bf16x8 a, bf16x8 b, f32x4 c) {
    return __builtin_amdgcn_mfma_f32_16x16x32_bf16(a, b, c, 0, 0, 0);
}
// perm layout, K=128 operands (theta/phi/g/y): frag-contiguous 1KB wave-loads
__device__ __forceinline__ size_t pidx(int r, int k) {
    return (size_t)((r >> 4) * 4 + (k >> 5)) * 512 +
           (size_t)(((k >> 3) & 3) * 128 + (r & 15) * 8 + (k & 7));
}
// perm layout, K=256 operands (conv A inputs)
__device__ __forceinline__ size_t pidx256(int r, int k) {
    return (size_t)((r >> 4) * 8 + (k >> 5)) * 512 +
           (size_t)(((k >> 3) & 3) * 128 + (r & 15) * 8 + (k & 7));
}

struct Frag3 { bf16x8 h, m, l; };
struct Frag2 { bf16x8 h, m; };

__device__ __forceinline__ Frag3 ld3(const short* __restrict__ h, const short* __restrict__ m,
                                     const short* __restrict__ l, size_t off) {
    Frag3 f;
    f.h = *(const bf16x8*)(h + off);
    f.m = *(const bf16x8*)(m + off);
    f.l = *(const bf16x8*)(l + off);
    return f;
}
__device__ __forceinline__ Frag2 ld2(const short* __restrict__ h, const short* __restrict__ m,
                                     size_t off) {
    Frag2 f;
    f.h = *(const bf16x8*)(h + off);
    f.m = *(const bf16x8*)(m + off);
    return f;
}
// 5-term conv product: A 2-plane (exact to 2^-17) x W 3-plane
__device__ __forceinline__ f32x4 mm5(Frag2 a, Frag3 w, f32x4 acc) {
    acc = mfma16(a.h, w.l, acc);
    acc = mfma16(a.m, w.m, acc);
    acc = mfma16(a.m, w.h, acc);
    acc = mfma16(a.h, w.m, acc);
    acc = mfma16(a.h, w.h, acc);
    return acc;
}
__device__ __forceinline__ f32x4 mm3(Frag2 a, Frag2 b, f32x4 acc) {
    acc = mfma16(a.m, b.h, acc);
    acc = mfma16(a.h, b.m, acc);
    acc = mfma16(a.h, b.h, acc);
    return acc;
}
// 2-term f-emulation: streamed operand h-plane only (drops a_m * b.h term,
// |err| ~ 2^-9*sqrt(128) ~ 0.03 in f) — S denominator AND stored P (consistent)
__device__ __forceinline__ f32x4 mm2s(bf16x8 ah, Frag2 b, f32x4 acc) {
    acc = mfma16(ah, b.m, acc);
    acc = mfma16(ah, b.h, acc);
    return acc;
}
// build PV A-frag from f^T tile pair (fallback path only)
__device__ __forceinline__ bf16x8 mk_pa(f32x4 f0, f32x4 f1, int srcLo, int srcHi, bool hiTile) {
    unsigned t0d0 = (unsigned)(unsigned short)f2bf(__expf(f0[0] - 32.f)) |
                    ((unsigned)(unsigned short)f2bf(__expf(f0[1] - 32.f)) << 16);
    unsigned t0d1 = (unsigned)(unsigned short)f2bf(__expf(f0[2] - 32.f)) |
                    ((unsigned)(unsigned short)f2bf(__expf(f0[3] - 32.f)) << 16);
    unsigned t1d0 = (unsigned)(unsigned short)f2bf(__expf(f1[0] - 32.f)) |
                    ((unsigned)(unsigned short)f2bf(__expf(f1[1] - 32.f)) << 16);
    unsigned t1d1 = (unsigned)(unsigned short)f2bf(__expf(f1[2] - 32.f)) |
                    ((unsigned)(unsigned short)f2bf(__expf(f1[3] - 32.f)) << 16);
    unsigned lo0t0 = __shfl(t0d0, srcLo), lo1t0 = __shfl(t0d1, srcLo);
    unsigned hi0t0 = __shfl(t0d0, srcHi), hi1t0 = __shfl(t0d1, srcHi);
    unsigned lo0t1 = __shfl(t1d0, srcLo), lo1t1 = __shfl(t1d1, srcLo);
    unsigned hi0t1 = __shfl(t1d0, srcHi), hi1t1 = __shfl(t1d1, srcHi);
    unsigned pd[4];
    pd[0] = hiTile ? lo0t1 : lo0t0;
    pd[1] = hiTile ? lo1t1 : lo1t0;
    pd[2] = hiTile ? hi0t1 : hi0t0;
    pd[3] = hiTile ? hi1t1 : hi1t0;
    bf16x8 pa;
    __builtin_memcpy(&pa, pd, 16);
    return pa;
}

// ---- merged weight pre-split: theta/phi 3-plane, g/W 2-plane ----
__global__ void k_splitw(const float* __restrict__ thw, const float* __restrict__ phw,
                         const float* __restrict__ gw, const float* __restrict__ Ww,
                         short* __restrict__ thwH, short* __restrict__ thwM, short* __restrict__ thwL,
                         short* __restrict__ phwH, short* __restrict__ phwM, short* __restrict__ phwL,
                         short* __restrict__ gwH, short* __restrict__ gwM,
                         short* __restrict__ wwH, short* __restrict__ wwM) {
    int i = blockIdx.x * 256 + threadIdx.x;
    int which = i >> 15, j = i & 32767;
    if (which == 0) {
        float x = thw[j];
        unsigned uh = __float_as_uint(x) & 0xffff0000u;
        float r1 = x - __uint_as_float(uh);
        unsigned um = __float_as_uint(r1) & 0xffff0000u;
        thwH[j] = (short)(uh >> 16);
        thwM[j] = (short)(um >> 16);
        thwL[j] = f2bf(r1 - __uint_as_float(um));
    } else if (which == 1) {
        float x = phw[j];
        unsigned uh = __float_as_uint(x) & 0xffff0000u;
        float r1 = x - __uint_as_float(uh);
        unsigned um = __float_as_uint(r1) & 0xffff0000u;
        phwH[j] = (short)(uh >> 16);
        phwM[j] = (short)(um >> 16);
        phwL[j] = f2bf(r1 - __uint_as_float(um));
    } else if (which == 2) {
        float x = gw[j];
        unsigned uh = __float_as_uint(x) & 0xffff0000u;
        gwH[j] = (short)(uh >> 16);
        gwM[j] = f2bf(x - __uint_as_float(uh));
    } else {
        float x = Ww[j];
        unsigned uh = __float_as_uint(x) & 0xffff0000u;
        wwH[j] = (short)(uh >> 16);
        wwM[j] = f2bf(x - __uint_as_float(uh));
    }
}

// ---- transpose + 2-plane split into perm(K=256) ----
__global__ void k_transpose2p(const float* __restrict__ src, short* __restrict__ oh,
                              short* __restrict__ om) {
    __shared__ float tile[32][33];
    int b = blockIdx.z;
    const float* s = src + (size_t)b * C_ * NPIX;
    size_t ob = (size_t)b * NPIX * C_;
    int p0 = blockIdx.x * 32, c0 = blockIdx.y * 32;
    for (int i = threadIdx.y; i < 32; i += 8)
        tile[i][threadIdx.x] = s[(size_t)(c0 + i) * NPIX + p0 + threadIdx.x];
    __syncthreads();
    for (int i = threadIdx.y; i < 32; i += 8) {
        float v = tile[threadIdx.x][i];
        unsigned uh = __float_as_uint(v) & 0xffff0000u;
        size_t o = ob + pidx256(p0 + i, c0 + threadIdx.x);
        oh[o] = (short)(uh >> 16);
        om[o] = f2bf(v - __uint_as_float(uh));
    }
}

// ---- theta conv: 5-term, 2 row-tiles/block. grid (NPIX/32, B), block 128 ----
__global__ __launch_bounds__(128, 2) void k_conv5(const short* __restrict__ AH,
        const short* __restrict__ AM,
        const short* __restrict__ WH, const short* __restrict__ WM, const short* __restrict__ WL,
        const float* __restrict__ bias, short* __restrict__ oh, short* __restrict__ om) {
    int wid = threadIdx.x >> 6, lane = threadIdx.x & 63;
    int quad = lane >> 4, l16 = lane & 15;
    int b = blockIdx.y;
    size_t ab = (size_t)b * NPIX * C_;
    size_t ob = (size_t)b * NPIX * CI_;
    int rt0 = blockIdx.x * 2;
    f32x4 acc[2][4] = {};
    for (int kt = 0; kt < 8; kt++) {
        Frag2 a0 = ld2(AH, AM, ab + ((size_t)rt0 * 8 + kt) * 512 + lane * 8);
        Frag2 a1 = ld2(AH, AM, ab + ((size_t)(rt0 + 1) * 8 + kt) * 512 + lane * 8);
#pragma unroll
        for (int c4 = 0; c4 < 4; c4++) {
            int c = (wid * 4 + c4) * 16 + l16;
            Frag3 w = ld3(WH, WM, WL, (size_t)c * C_ + kt * 32 + quad * 8);
            acc[0][c4] = mm5(a0, w, acc[0][c4]);
            acc[1][c4] = mm5(a1, w, acc[1][c4]);
        }
    }
#pragma unroll
    for (int t2 = 0; t2 < 2; t2++)
#pragma unroll
        for (int c4 = 0; c4 < 4; c4++) {
            int c = (wid * 4 + c4) * 16 + l16;
            float bv = bias[c];
#pragma unroll
            for (int r = 0; r < 4; r++) {
                float v = acc[t2][c4][r] + bv;
                unsigned uh = __float_as_uint(v) & 0xffff0000u;
                size_t o = ob + pidx((rt0 + t2) * 16 + quad * 4 + r, c);
                oh[o] = (short)(uh >> 16);
                om[o] = f2bf(v - __uint_as_float(uh));
            }
        }
}

// ---- fused phi(5-term->fp32) + g(3-term->bf16), 2 row-tiles/block ----
__global__ __launch_bounds__(128, 2) void k_convxg5(const short* __restrict__ AH,
        const short* __restrict__ AM,
        const short* __restrict__ PH, const short* __restrict__ PM, const short* __restrict__ PL,
        const short* __restrict__ GH, const short* __restrict__ GM,
        const float* __restrict__ pbias, const float* __restrict__ gbias,
        float* __restrict__ pfull, short* __restrict__ gout) {
    int wid = threadIdx.x >> 6, lane = threadIdx.x & 63;
    int quad = lane >> 4, l16 = lane & 15;
    int b = blockIdx.y;
    size_t ab = (size_t)b * NPIX * C_;
    float* Pb = pfull + (size_t)b * NPIX * CI_;
    short* Gb = gout + (size_t)b * NPIX * CI_;
    int rt0 = blockIdx.x * 2;
    f32x4 accp[2][4] = {}, accg[2][4] = {};
    for (int kt = 0; kt < 8; kt++) {
        Frag2 a0 = ld2(AH, AM, ab + ((size_t)rt0 * 8 + kt) * 512 + lane * 8);
        Frag2 a1 = ld2(AH, AM, ab + ((size_t)(rt0 + 1) * 8 + kt) * 512 + lane * 8);
#pragma unroll
        for (int c4 = 0; c4 < 4; c4++) {
            int c = (wid * 4 + c4) * 16 + l16;
            size_t wo = (size_t)c * C_ + kt * 32 + quad * 8;
            Frag3 wp = ld3(PH, PM, PL, wo);
            accp[0][c4] = mm5(a0, wp, accp[0][c4]);
            accp[1][c4] = mm5(a1, wp, accp[1][c4]);
            Frag2 wg = ld2(GH, GM, wo);
            accg[0][c4] = mm3(a0, wg, accg[0][c4]);
            accg[1][c4] = mm3(a1, wg, accg[1][c4]);
        }
    }
#pragma unroll
    for (int t2 = 0; t2 < 2; t2++)
#pragma unroll
        for (int c4 = 0; c4 < 4; c4++) {
            int c = (wid * 4 + c4) * 16 + l16;
            float pbv = pbias[c], gbv = gbias[c];
#pragma unroll
            for (int r = 0; r < 4; r++) {
                size_t o = (size_t)((rt0 + t2) * 16 + quad * 4 + r) * CI_ + c;
                Pb[o] = accp[t2][c4][r] + pbv;
                Gb[o] = f2bf(accg[t2][c4][r] + gbv);
            }
        }
}

// ---- pool: pfull fp32 -> phi 2-plane PERM; gfull bf16 -> gcf fp32 (ci, m) ----
__global__ void k_pool(const float* __restrict__ pfull, const short* __restrict__ gfull,
                       short* __restrict__ pth, short* __restrict__ ptm,
                       float* __restrict__ gcf) {
    int b = blockIdx.y;
    int idx = blockIdx.x * 256 + threadIdx.x;       // idx = m*128 + ci
    int ci = idx & 127, m = idx >> 7;
    int t = m / 196, r2i = m - t * 196;
    int h2 = r2i / 14, w2 = r2i - h2 * 14;
    size_t p = (size_t)t * 784 + (size_t)(2 * h2) * 28 + 2 * w2;
    size_t i0 = (size_t)b * NPIX * CI_ + p * CI_ + ci;
    float pv = fmaxf(fmaxf(pfull[i0], pfull[i0 + CI_]),
                     fmaxf(pfull[i0 + 28 * CI_], pfull[i0 + 29 * CI_]));
    unsigned uh = __float_as_uint(pv) & 0xffff0000u;
    size_t ob = (size_t)b * NS * CI_ + pidx(m, ci);
    pth[ob] = (short)(uh >> 16);
    ptm[ob] = f2bf(pv - __uint_as_float(uh));
    float g0 = fmaxf(fmaxf(bf2f(gfull[i0]), bf2f(gfull[i0 + CI_])),
                     fmaxf(bf2f(gfull[i0 + 28 * CI_]), bf2f(gfull[i0 + 29 * CI_])));
    gcf[(size_t)b * NS * CI_ + (size_t)ci * NS + m] = g0;
}

// ---- stats+P: S[m]=sum_n exp(f-32) AND store P=exp(f-32) bf16 in PV-A perm.
//      XCD-pinned wgid = (tchunk*2+b) + 56*x. grid (49*56), block 128 ----
__global__ __launch_bounds__(128, 2) void k_statsP(
        const short* __restrict__ thh, const short* __restrict__ phh,
        const short* __restrict__ phm, float* __restrict__ Spart,
        short* __restrict__ Pbuf) {
    int wid = threadIdx.x >> 6, lane = threadIdx.x & 63;
    int quad = lane >> 4, l16 = lane & 15;
    int wg = blockIdx.x;
    int p = wg % 56;
    int bx = wg / 56;
    int b = p & 1, ychunk = p >> 1;
    size_t tb = (size_t)b * NPIX * CI_, pb = (size_t)b * NS * CI_;
    short* PB = Pbuf + (size_t)b * NPIX * NS;
    int mtA = bx * 4 + wid * 2;                     // m-tiles mtA (even), mtA+1
    Frag2 bfA[4], bfB[4];
#pragma unroll
    for (int kk = 0; kk < 4; kk++) {
        bfA[kk] = ld2(phh, phm, pb + ((size_t)mtA * 4 + kk) * 512 + lane * 8);
        bfB[kk] = ld2(phh, phm, pb + ((size_t)(mtA + 1) * 4 + kk) * 512 + lane * 8);
    }
    float SA = 0.f, SB = 0.f;
    int t_beg = ychunk * (784 / NSL), t_end = t_beg + 784 / NSL;
    int kg = mtA >> 1;                              // 32-m group index of P
    // lane's scatter base within a C-tile: subk*128 + (quad*4+r)*8 + (m&7)
    size_t laneoff = (size_t)(l16 >> 3) * 128 + (l16 & 7) + (size_t)quad * 32;
    for (int t = t_beg; t < t_end; t += 2) {
        f32x4 aA0 = {}, aA1 = {}, aB0 = {}, aB1 = {};
#pragma unroll
        for (int kk = 0; kk < 4; kk++) {
            bf16x8 x0 = *(const bf16x8*)(thh + tb + ((size_t)t * 4 + kk) * 512 + lane * 8);
            bf16x8 x1 = *(const bf16x8*)(thh + tb + ((size_t)(t + 1) * 4 + kk) * 512 + lane * 8);
            aA0 = mm2s(x0, bfA[kk], aA0);
            aA1 = mm2s(x1, bfA[kk], aA1);
            aB0 = mm2s(x0, bfB[kk], aB0);
            aB1 = mm2s(x1, bfB[kk], aB1);
        }
        size_t cA0 = ((size_t)t * 98 + kg) * 512 + laneoff;         // tile (t, mtA)
        size_t cA1 = cA0 + 98 * 512;                                // (t+1, mtA)
        size_t cB0 = cA0 + 256;                                     // (t, mtA+1)
        size_t cB1 = cA1 + 256;                                     // (t+1, mtA+1)
#pragma unroll
        for (int r = 0; r < 4; r++) {
            float eA0 = __expf(aA0[r] - 32.f); SA += eA0; PB[cA0 + r * 8] = f2bf(eA0);
            float eA1 = __expf(aA1[r] - 32.f); SA += eA1; PB[cA1 + r * 8] = f2bf(eA1);
            float eB0 = __expf(aB0[r] - 32.f); SB += eB0; PB[cB0 + r * 8] = f2bf(eB0);
            float eB1 = __expf(aB1[r] - 32.f); SB += eB1; PB[cB1 + r * 8] = f2bf(eB1);
        }
    }
    SA += __shfl_xor(SA, 16, 64); SA += __shfl_xor(SA, 32, 64);
    SB += __shfl_xor(SB, 16, 64); SB += __shfl_xor(SB, 32, 64);
    if (quad == 0) {
        size_t o = ((size_t)(b * NSL + ychunk)) * NS;
        Spart[o + mtA * 16 + l16] = SA;
        Spart[o + (mtA + 1) * 16 + l16] = SB;
    }
}

// ---- fallback stats (no P store) — r17 verified ----
__global__ __launch_bounds__(128, 2) void k_stats(
        const short* __restrict__ thh, const short* __restrict__ phh,
        const short* __restrict__ phm, float* __restrict__ Spart) {
    int wid = threadIdx.x >> 6, lane = threadIdx.x & 63;
    int quad = lane >> 4, l16 = lane & 15;
    int wg = blockIdx.x;
    int p = wg % 56;
    int bx = wg / 56;
    int b = p & 1, ychunk = p >> 1;
    size_t tb = (size_t)b * NPIX * CI_, pb = (size_t)b * NS * CI_;
    int mtA = bx * 4 + wid * 2;
    Frag2 bfA[4], bfB[4];
#pragma unroll
    for (int kk = 0; kk < 4; kk++) {
        bfA[kk] = ld2(phh, phm, pb + ((size_t)mtA * 4 + kk) * 512 + lane * 8);
        bfB[kk] = ld2(phh, phm, pb + ((size_t)(mtA + 1) * 4 + kk) * 512 + lane * 8);
    }
    float SA = 0.f, SB = 0.f;
    int t_beg = ychunk * (784 / NSL), t_end = t_beg + 784 / NSL;
    for (int t = t_beg; t < t_end; t += 2) {
        f32x4 aA0 = {}, aA1 = {}, aB0 = {}, aB1 = {};
#pragma unroll
        for (int kk = 0; kk < 4; kk++) {
            bf16x8 x0 = *(const bf16x8*)(thh + tb + ((size_t)t * 4 + kk) * 512 + lane * 8);
            bf16x8 x1 = *(const bf16x8*)(thh + tb + ((size_t)(t + 1) * 4 + kk) * 512 + lane * 8);
            aA0 = mm2s(x0, bfA[kk], aA0);
            aA1 = mm2s(x1, bfA[kk], aA1);
            aB0 = mm2s(x0, bfB[kk], aB0);
            aB1 = mm2s(x1, bfB[kk], aB1);
        }
        SA += __expf(aA0[0] - 32.f) + __expf(aA0[1] - 32.f) +
              __expf(aA0[2] - 32.f) + __expf(aA0[3] - 32.f) +
              __expf(aA1[0] - 32.f) + __expf(aA1[1] - 32.f) +
              __expf(aA1[2] - 32.f) + __expf(aA1[3] - 32.f);
        SB += __expf(aB0[0] - 32.f) + __expf(aB0[1] - 32.f) +
              __expf(aB0[2] - 32.f) + __expf(aB0[3] - 32.f) +
              __expf(aB1[0] - 32.f) + __expf(aB1[1] - 32.f) +
              __expf(aB1[2] - 32.f) + __expf(aB1[3] - 32.f);
    }
    SA += __shfl_xor(SA, 16, 64); SA += __shfl_xor(SA, 32, 64);
    SB += __shfl_xor(SB, 16, 64); SB += __shfl_xor(SB, 32, 64);
    if (quad == 0) {
        size_t o = ((size_t)(b * NSL + ychunk)) * NS;
        Spart[o + mtA * 16 + l16] = SA;
        Spart[o + (mtA + 1) * 16 + l16] = SB;
    }
}

__global__ void k_combine(const float* __restrict__ Spart, float* __restrict__ wS) {
    int i = blockIdx.x * 256 + threadIdx.x;
    if (i >= B_ * NS) return;
    int b = i / NS, m = i - b * NS;
    float s = 0.f;
#pragma unroll
    for (int sl = 0; sl < NSL; sl++)
        s += Spart[((size_t)(b * NSL + sl)) * NS + m];
    wS[i] = 1.f / s;
}

// ---- g scale into PV-B perm layout ----
__global__ void k_gscale(const float* __restrict__ gcf, const float* __restrict__ wS,
                         short* __restrict__ gc) {
    int i = blockIdx.x * 256 + threadIdx.x;         // B*CI*(NS/8) threads
    int b = i / (CI_ * (NS / 8));
    int rem = i - b * CI_ * (NS / 8);
    int c = rem / (NS / 8);
    int m8 = rem - c * (NS / 8);
    int m = m8 * 8;
    const float* gr = gcf + ((size_t)b * CI_ + c) * NS + m;
    const float* wr = wS + (size_t)b * NS + m;
    short* go = gc + (size_t)b * NS * CI_ + ((size_t)(m8 >> 2) * 8 + (c >> 4)) * 512 +
                (m8 & 3) * 128 + (c & 15) * 8;
#pragma unroll
    for (int j = 0; j < 8; j++) go[j] = f2bf(gr[j] * wr[j]);
}

// ---- PV-GEMM: y = P @ ghat. Wave: 2 n-tiles, m-slice x4, fp16 partials.
//      Per k-step: 2 A-frag + 8 B-frag loads, 16 mfma. XCD-pinned.
//      grid (1568), block 128 ----
__global__ __launch_bounds__(128, 2) void k_pvP(
        const short* __restrict__ Pbuf, const short* __restrict__ gp,
        short* __restrict__ part) {
    int wid = threadIdx.x >> 6, lane = threadIdx.x & 63;
    int quad = lane >> 4, l16 = lane & 15;
    int wg = blockIdx.x;
    int pair = wg & 7;                              // (slice, b) -> pins XCD
    int bx = wg >> 3;                               // 0..195
    int slice = pair >> 1, b = pair & 1;
    int ntA = bx * 4 + wid * 2;                     // n-tiles ntA, ntA+1
    const short* PB = Pbuf + (size_t)b * NPIX * NS;
    const short* gpb = gp + (size_t)b * NS * CI_;
    f32x4 yaccA[8] = {}, yaccB[8] = {};
    int s_beg = slice * 24 + (slice < 2 ? slice : 2);   // {25,25,24,24} of 98
    int s_end = s_beg + 24 + (slice < 2 ? 1 : 0);
    const short* pA = PB + ((size_t)ntA * 98 + s_beg) * 512 + lane * 8;
    const short* pBp = PB + ((size_t)(ntA + 1) * 98 + s_beg) * 512 + lane * 8;
    const short* gb = gpb + (size_t)s_beg * 4096 + lane * 8;
#pragma unroll 2
    for (int s = s_beg; s < s_end; s++) {
        bf16x8 pa0 = *(const bf16x8*)pA;
        bf16x8 pa1 = *(const bf16x8*)pBp;
        bf16x8 g0 = *(const bf16x8*)(gb + 0 * 512);
        bf16x8 g1 = *(const bf16x8*)(gb + 1 * 512);
        bf16x8 g2 = *(const bf16x8*)(gb + 2 * 512);
        bf16x8 g3 = *(const bf16x8*)(gb + 3 * 512);
        bf16x8 g4 = *(const bf16x8*)(gb + 4 * 512);
        bf16x8 g5 = *(const bf16x8*)(gb + 5 * 512);
        bf16x8 g6 = *(const bf16x8*)(gb + 6 * 512);
        bf16x8 g7 = *(const bf16x8*)(gb + 7 * 512);
        pA += 512; pBp += 512; gb += 4096;
        yaccA[0] = mfma16(pa0, g0, yaccA[0]); yaccB[0] = mfma16(pa1, g0, yaccB[0]);
        yaccA[1] = mfma16(pa0, g1, yaccA[1]); yaccB[1] = mfma16(pa1, g1, yaccB[1]);
        yaccA[2] = mfma16(pa0, g2, yaccA[2]); yaccB[2] = mfma16(pa1, g2, yaccB[2]);
        yaccA[3] = mfma16(pa0, g3, yaccA[3]); yaccB[3] = mfma16(pa1, g3, yaccB[3]);
        yaccA[4] = mfma16(pa0, g4, yaccA[4]); yaccB[4] = mfma16(pa1, g4, yaccB[4]);
        yaccA[5] = mfma16(pa0, g5, yaccA[5]); yaccB[5] = mfma16(pa1, g5, yaccB[5]);
        yaccA[6] = mfma16(pa0, g6, yaccA[6]); yaccB[6] = mfma16(pa1, g6, yaccB[6]);
        yaccA[7] = mfma16(pa0, g7, yaccA[7]); yaccB[7] = mfma16(pa1, g7, yaccB[7]);
    }
    short* po = part + ((size_t)slice * B_ + b) * NPIX * CI_;
#pragma unroll
    for (int cc = 0; cc < 8; cc++)
#pragma unroll
        for (int r = 0; r < 4; r++) {
            po[pidx(ntA * 16 + quad * 4 + r, cc * 16 + l16)] = f2h(yaccA[cc][r]);
            po[pidx((ntA + 1) * 16 + quad * 4 + r, cc * 16 + l16)] = f2h(yaccB[cc][r]);
        }
}

// ---- fallback PV (recompute-f) — r17 verified ----
__global__ __launch_bounds__(128, 2) void k_pv(
        const short* __restrict__ thh, const short* __restrict__ thm,
        const short* __restrict__ phh, const short* __restrict__ phm,
        const short* __restrict__ gp, short* __restrict__ part) {
    int wid = threadIdx.x >> 6, lane = threadIdx.x & 63;
    int quad = lane >> 4, l16 = lane & 15;
    int wg = blockIdx.x;
    int pair = wg & 7;
    int bx = wg >> 3;
    int slice = pair >> 1, b = pair & 1;
    int ntA = bx * 4 + wid * 2;
    size_t tb = (size_t)b * NPIX * CI_, pb = (size_t)b * NS * CI_;
    const short* gpb = gp + (size_t)b * NS * CI_;
    Frag2 afA[4], afB[4];
#pragma unroll
    for (int kk = 0; kk < 4; kk++) {
        afA[kk] = ld2(thh, thm, tb + ((size_t)ntA * 4 + kk) * 512 + lane * 8);
        afB[kk] = ld2(thh, thm, tb + ((size_t)(ntA + 1) * 4 + kk) * 512 + lane * 8);
    }
    f32x4 yaccA[8] = {}, yaccB[8] = {};
    int srcLo = ((2 * quad) & 3) * 16 + l16;
    int srcHi = ((2 * quad + 1) & 3) * 16 + l16;
    bool hiTile = quad >= 2;
    int s_beg = slice * 24 + (slice < 2 ? slice : 2);
    int s_end = s_beg + 24 + (slice < 2 ? 1 : 0);
    for (int s = s_beg; s < s_end; s++) {
        bf16x8 gf0 = *(const bf16x8*)(gpb + (size_t)s * 4096 + 0 * 512 + lane * 8);
        bf16x8 gf1 = *(const bf16x8*)(gpb + (size_t)s * 4096 + 1 * 512 + lane * 8);
        bf16x8 gf2 = *(const bf16x8*)(gpb + (size_t)s * 4096 + 2 * 512 + lane * 8);
        bf16x8 gf3 = *(const bf16x8*)(gpb + (size_t)s * 4096 + 3 * 512 + lane * 8);
        bf16x8 gf4 = *(const bf16x8*)(gpb + (size_t)s * 4096 + 4 * 512 + lane * 8);
        bf16x8 gf5 = *(const bf16x8*)(gpb + (size_t)s * 4096 + 5 * 512 + lane * 8);
        bf16x8 gf6 = *(const bf16x8*)(gpb + (size_t)s * 4096 + 6 * 512 + lane * 8);
        bf16x8 gf7 = *(const bf16x8*)(gpb + (size_t)s * 4096 + 7 * 512 + lane * 8);
        f32x4 fA0 = {}, fA1 = {}, fB0 = {}, fB1 = {};
#pragma unroll
        for (int kk = 0; kk < 4; kk++) {
            Frag2 p0 = ld2(phh, phm, pb + ((size_t)(2 * s) * 4 + kk) * 512 + lane * 8);
            Frag2 p1 = ld2(phh, phm, pb + ((size_t)(2 * s + 1) * 4 + kk) * 512 + lane * 8);
            fA0 = mm3(p0, afA[kk], fA0);
            fA1 = mm3(p1, afA[kk], fA1);
            fB0 = mm3(p0, afB[kk], fB0);
            fB1 = mm3(p1, afB[kk], fB1);
        }
        bf16x8 paA = mk_pa(fA0, fA1, srcLo, srcHi, hiTile);
        bf16x8 paB = mk_pa(fB0, fB1, srcLo, srcHi, hiTile);
        yaccA[0] = mfma16(paA, gf0, yaccA[0]); yaccB[0] = mfma16(paB, gf0, yaccB[0]);
        yaccA[1] = mfma16(paA, gf1, yaccA[1]); yaccB[1] = mfma16(paB, gf1, yaccB[1]);
        yaccA[2] = mfma16(paA, gf2, yaccA[2]); yaccB[2] = mfma16(paB, gf2, yaccB[2]);
        yaccA[3] = mfma16(paA, gf3, yaccA[3]); yaccB[3] = mfma16(paB, gf3, yaccB[3]);
        yaccA[4] = mfma16(paA, gf4, yaccA[4]); yaccB[4] = mfma16(paB, gf4, yaccB[4]);
        yaccA[5] = mfma16(paA, gf5, yaccA[5]); yaccB[5] = mfma16(paB, gf5, yaccB[5]);
        yaccA[6] = mfma16(paA, gf6, yaccA[6]); yaccB[6] = mfma16(paB, gf6, yaccB[6]);
        yaccA[7] = mfma16(paA, gf7, yaccA[7]); yaccB[7] = mfma16(paB, gf7, yaccB[7]);
    }
    short* po = part + ((size_t)slice * B_ + b) * NPIX * CI_;
#pragma unroll
    for (int cc = 0; cc < 8; cc++)
#pragma unroll
        for (int r = 0; r < 4; r++) {
            po[pidx(ntA * 16 + quad * 4 + r, cc * 16 + l16)] = f2h(yaccA[cc][r]);
            po[pidx((ntA + 1) * 16 + quad * 4 + r, cc * 16 + l16)] = f2h(yaccB[cc][r]);
        }
}

// ---- combine 4 fp16 y-partials -> 2-plane bf16 (perm order preserved) ----
__global__ void k_ycombine(const short* __restrict__ part, short* __restrict__ yh,
                           short* __restrict__ ym) {
    size_t i = (size_t)blockIdx.x * 256 + threadIdx.x;
    const size_t n = (size_t)B_ * NPIX * CI_;
    if (i >= n) return;
    float v = h2f(part[i]) + h2f(part[n + i]) + h2f(part[2 * n + i]) + h2f(part[3 * n + i]);
    unsigned uh = __float_as_uint(v) & 0xffff0000u;
    yh[i] = (short)(uh >> 16);
    ym[i] = f2bf(v - __uint_as_float(uh));
}

// ---- W conv (3-term, perm y reads) + BN partials (NO atomics: LDS cross-wave
//      reduce + one 1KB store/block). grid (NPIX/64, C_/128, B), block 256 ----
__global__ __launch_bounds__(256) void k_wconv3(const short* __restrict__ yh,
        const short* __restrict__ ym, const short* __restrict__ WH,
        const short* __restrict__ WM, const float* __restrict__ bias,
        float* __restrict__ Wy, float* __restrict__ pstat) {
    __shared__ float sm1[4][128], sm2[4][128];
    int wid = threadIdx.x >> 6, lane = threadIdx.x & 63;
    int quad = lane >> 4, l16 = lane & 15;
    int b = blockIdx.z;
    size_t yb = (size_t)b * NPIX * CI_;
    float* Wyb = Wy + (size_t)b * NPIX * C_;
    int tile = blockIdx.x * 4 + wid;
    int row0 = tile * 16;
    int col0 = blockIdx.y * 128;
    f32x4 acc[8] = {};
#pragma unroll
    for (int kk = 0; kk < 4; kk++) {
        size_t ao = yb + ((size_t)tile * 4 + kk) * 512 + lane * 8;
        bf16x8 ah = *(const bf16x8*)(yh + ao);
        bf16x8 am = *(const bf16x8*)(ym + ao);
#pragma unroll
        for (int cc = 0; cc < 8; cc++) {
            Frag2 w = ld2(WH, WM, (size_t)(col0 + cc * 16 + l16) * CI_ + kk * 32 + quad * 8);
            acc[cc] = mfma16(am, w.h, acc[cc]);
            acc[cc] = mfma16(ah, w.m, acc[cc]);
            acc[cc] = mfma16(ah, w.h, acc[cc]);
        }
    }
#pragma unroll
    for (int cc = 0; cc < 8; cc++) {
        int c = col0 + cc * 16 + l16;
        float bv = bias[c];
        float s1 = 0.f, s2 = 0.f;
#pragma unroll
        for (int r = 0; r < 4; r++) {
            float v = acc[cc][r] + bv;
            Wyb[(size_t)(row0 + quad * 4 + r) * C_ + c] = v;
            s1 += v;
            s2 += v * v;
        }
        s1 += __shfl_xor(s1, 16, 64); s1 += __shfl_xor(s1, 32, 64);
        s2 += __shfl_xor(s2, 16, 64); s2 += __shfl_xor(s2, 32, 64);
        if (quad == 0) {
            sm1[wid][cc * 16 + l16] = s1;
            sm2[wid][cc * 16 + l16] = s2;
        }
    }
    __syncthreads();
    // one coalesced partial store per block: pstat[((b*2+by)*196+bx)*256 + {0..255}]
    int tid = threadIdx.x;
    size_t base = (((size_t)b * 2 + blockIdx.y) * 196 + blockIdx.x) * 256;
    if (tid < 128) {
        float v = sm1[0][tid] + sm1[1][tid] + sm1[2][tid] + sm1[3][tid];
        pstat[base + tid] = v;
    } else {
        int chl = tid - 128;
        float v = sm2[0][chl] + sm2[1][chl] + sm2[2][chl] + sm2[3][chl];
        pstat[base + 128 + chl] = v;
    }
}

// ---- BN finalize: reduce 392 partials per channel, compute scale/shift ----
__global__ void k_bnfin(const float* __restrict__ pstat, const float* __restrict__ gamma,
                        const float* __restrict__ beta, float* __restrict__ sc,
                        float* __restrict__ sh) {
    int c = threadIdx.x;                            // 0..255
    int by = c >> 7, chl = c & 127;
    float s1 = 0.f, s2 = 0.f;
    for (int b = 0; b < B_; b++)
        for (int bx = 0; bx < 196; bx++) {
            size_t idx = (((size_t)b * 2 + by) * 196 + bx) * 256;
            s1 += pstat[idx + chl];
            s2 += pstat[idx + 128 + chl];
        }
    const float inv = 1.f / (float)(B_ * NPIX);
    float mean = s1 * inv;
    float var = s2 * inv - mean * mean;
    float s = gamma[c] * rsqrtf(var + 1e-5f);
    sc[c] = s;
    sh[c] = beta[c] - mean * s;
}

__global__ void k_final(const float* __restrict__ Wy, const float* __restrict__ x,
                        const float* __restrict__ sc, const float* __restrict__ sh,
                        float* __restrict__ out) {
    __shared__ float tile[32][33];
    int b = blockIdx.z;
    const float* Wyb = Wy + (size_t)b * NPIX * C_;
    const float* xb = x + (size_t)b * C_ * NPIX;
    float* ob = out + (size_t)b * C_ * NPIX;
    int p0 = blockIdx.x * 32, c0 = blockIdx.y * 32;
    for (int i = threadIdx.y; i < 32; i += 8)
        tile[i][threadIdx.x] = Wyb[(size_t)(p0 + i) * C_ + c0 + threadIdx.x];
    __syncthreads();
    for (int i = threadIdx.y; i < 32; i += 8) {
        int c = c0 + i;
        size_t o = (size_t)c * NPIX + p0 + threadIdx.x;
        ob[o] = tile[threadIdx.x][i] * sc[c] + sh[c] + xb[o];
    }
}

extern "C" void kernel_launch(void* const* d_in, const int* in_sizes, int n_in,
                              void* d_out, int out_size, void* d_ws, size_t ws_size,
                              hipStream_t stream) {
    (void)in_sizes; (void)n_in; (void)out_size;
    const float* x     = (const float*)d_in[0];
    const float* mask  = (const float*)d_in[1];
    const float* g_w   = (const float*)d_in[2];
    const float* g_b   = (const float*)d_in[3];
    const float* th_w  = (const float*)d_in[4];
    const float* th_b  = (const float*)d_in[5];
    const float* ph_w  = (const float*)d_in[6];
    const float* ph_b  = (const float*)d_in[7];
    const float* W_w   = (const float*)d_in[8];
    const float* W_b   = (const float*)d_in[9];
    const float* gamma = (const float*)d_in[10];
    const float* beta  = (const float*)d_in[11];
    float* out = (float*)d_out;

    char* ws = (char*)d_ws;
    // [0, 25.69MB) timeline: A-planes -> {gcf,Spart,wS} -> part (4 slices fp16) -> Wy
    short* AH    = (short*)(ws + 0);              // 12,845,056
    short* AM    = (short*)(ws + 12845056);       // 12,845,056
    float* gcf   = (float*)(ws + 0);              // 3,211,264 (pool -> gscale)
    float* Spart = (float*)(ws + 4194304);        // 702,464 (NSL=28)
    float* wS    = (float*)(ws + 5242880);        // 25,088
    short* part  = (short*)(ws + 0);              // 25,690,112 = 4 x 6,422,528 (fp16)
    float* Wy    = (float*)(ws + 0);              // 25,690,112 (wconv -> final)
    short* thH   = (short*)(ws + 25690112);       // 6,422,528 (perm)
    short* thM   = (short*)(ws + 32112640);       // 6,422,528 (perm)
    short* wwH   = (short*)(ws + 38535168);       // 65,536 x2
    short* wwM   = wwH + 32768;
    float* pfull = (float*)(ws + 44957696);       // 12,845,056 (pre-pool)
    short* yH    = (short*)(ws + 44957696);       // alias after pool (perm)
    short* yM    = (short*)(ws + 51380224);       // (perm)
    short* gfull = (short*)(ws + 57802752);       // 6,422,528
    short* thwH  = (short*)(ws + 64225280);       // weight scratch (dead after convs)
    short* thwM  = thwH + 32768;
    short* thwL  = thwM + 32768;
    short* phwH  = thwL + 32768;
    short* phwM  = phwH + 32768;
    short* phwL  = phwM + 32768;
    short* gwH   = phwL + 32768;
    short* gwM   = gwH + 32768;
    short* ptH   = (short*)(ws + 64225280);       // 1,605,632 (perm, after convs)
    short* ptM   = (short*)(ws + 65830912);       // 1,605,632 (perm)
    float* pstat = (float*)(ws + 64225280);       // 802,816 (aliases DEAD ptH:
                                                  // pt* unused after statsP/pv)
    short* gc    = (short*)(ws + 69042176);       // 1,605,632 (perm, scaled)
    float* sc    = (float*)(ws + 71101440);       // 1,024
    float* sh    = (float*)(ws + 71102464);       // 1,024
    // P buffer (bf16, PV-A perm): [71303168, 228655104) — gated on ws_size
    const size_t pOff = 71303168ull;
    const size_t pBytes = (size_t)B_ * NPIX * NS * sizeof(short);   // 157,351,936
    bool bigws = ws_size >= pOff + pBytes;
    short* Pbuf = (short*)(ws + pOff);

    k_splitw<<<512, 256, 0, stream>>>(th_w, ph_w, g_w, W_w, thwH, thwM, thwL,
                                      phwH, phwM, phwL, gwH, gwM, wwH, wwM);

    dim3 tb32(32, 8);
    k_transpose2p<<<dim3(NPIX / 32, C_ / 32, B_), tb32, 0, stream>>>(mask, AH, AM);
    k_conv5<<<dim3(NPIX / 32, B_), 128, 0, stream>>>(AH, AM, thwH, thwM, thwL, th_b, thH, thM);

    k_transpose2p<<<dim3(NPIX / 32, C_ / 32, B_), tb32, 0, stream>>>(x, AH, AM);
    k_convxg5<<<dim3(NPIX / 32, B_), 128, 0, stream>>>(AH, AM, phwH, phwM, phwL, gwH, gwM,
                                                       ph_b, g_b, pfull, gfull);

    k_pool<<<dim3(NS * CI_ / 256, B_), 256, 0, stream>>>(pfull, gfull, ptH, ptM, gcf);

    if (bigws)
        k_statsP<<<49 * 56, 128, 0, stream>>>(thH, ptH, ptM, Spart, Pbuf);
    else
        k_stats<<<49 * 56, 128, 0, stream>>>(thH, ptH, ptM, Spart);
    k_combine<<<(B_ * NS + 255) / 256, 256, 0, stream>>>(Spart, wS);
    k_gscale<<<(B_ * CI_ * (NS / 8)) / 256, 256, 0, stream>>>(gcf, wS, gc);

    if (bigws)
        k_pvP<<<196 * 8, 128, 0, stream>>>(Pbuf, gc, part);
    else
        k_pv<<<196 * 8, 128, 0, stream>>>(thH, thM, ptH, ptM, gc, part);

    k_ycombine<<<(int)(((size_t)B_ * NPIX * CI_ + 255) / 256), 256, 0, stream>>>(part, yH, yM);

    k_wconv3<<<dim3(NPIX / 64, C_ / 128, B_), 256, 0, stream>>>(yH, yM, wwH, wwM, W_b, Wy, pstat);
    k_bnfin<<<1, 256, 0, stream>>>(pstat, gamma, beta, sc, sh);
    k_final<<<dim3(NPIX / 32, C_ / 32, B_), tb32, 0, stream>>>(Wy, x, sc, sh, out);
}